// Round 3
// baseline (392.043 us; speedup 1.0000x reference)
//
#include <hip/hip_runtime.h>
#include <hip/hip_bf16.h>

// Causal SDPA, B=8, S=4096, D=64, fp32 in/out.
// Outputs: O [8,4096,64] then attention P [8,4096,4096], concatenated in d_out.
//
// Round 2: k_pwrite rewritten as a barrier-free, LDS-free write streamer.
//  - Swapped QK^T: mfma(A=K_frag, B=Q_frag) -> D[k][q]; with verified C/D layout
//    (col=lane&15 -> q-row, row=(lane>>4)*4+r -> k-col) each lane holds 4
//    consecutive k-cols of one P row => one dwordx4 store per 16x16 subtile.
//  - K fragments loaded directly from global (LLC-resident), no staging.
//  - One row-sum per lane (its q-row). No LDS, no __syncthreads in k_pwrite.
// k_sumo / k_ored unchanged from round 1.

#define S_LEN 4096
#define D_DIM 64

typedef float f32x4 __attribute__((ext_vector_type(4)));
typedef short bf16x8 __attribute__((ext_vector_type(8)));
typedef unsigned short u16;

// ws layout (floats): wsRow [8][64][8][64] = 262144, then wsO [8][64][8][4096]
#define WSROW_FLOATS (262144)
#define WSO_FLOATS   ((size_t)8 * 64 * 8 * 4096)

__device__ __forceinline__ u16 f2bf(float f) {
  union { float f; unsigned u; } x; x.f = f;
  unsigned r = x.u + 0x7fff + ((x.u >> 16) & 1);  // RNE
  return (u16)(r >> 16);
}
__device__ __forceinline__ float bf2f(short h) {
  return __uint_as_float(((unsigned)(unsigned short)h) << 16);
}
__device__ __forceinline__ bf16x8 pack8(f32x4 a, f32x4 b) {
  bf16x8 r;
  r[0] = (short)f2bf(a[0]); r[1] = (short)f2bf(a[1]);
  r[2] = (short)f2bf(a[2]); r[3] = (short)f2bf(a[3]);
  r[4] = (short)f2bf(b[0]); r[5] = (short)f2bf(b[1]);
  r[6] = (short)f2bf(b[2]); r[7] = (short)f2bf(b[3]);
  return r;
}

__device__ __forceinline__ void stageK_fn(u16* Ks, const float* src, int t) {
  int linear = t;
#pragma unroll
  for (int j = 0; j < 4; ++j, linear += 256) {
    int r = linear >> 4, cq = linear & 15;
    f32x4 v = *(const f32x4*)(src + r * D_DIM + cq * 4);
    unsigned lo = (unsigned)f2bf(v[0]) | ((unsigned)f2bf(v[1]) << 16);
    unsigned hi = (unsigned)f2bf(v[2]) | ((unsigned)f2bf(v[3]) << 16);
    int byte = r * 128 + ((cq * 8) ^ ((r & 7) << 4));
    *(unsigned long long*)((char*)Ks + byte) =
        (unsigned long long)lo | ((unsigned long long)hi << 32);
  }
}

__device__ __forceinline__ void stageV_fn(u16* VTs, const float* src, int t) {
  int kk = t >> 2;
  int dbase = (t & 3) * 16;
  const float* s = src + (size_t)kk * D_DIM + dbase;
#pragma unroll
  for (int j4 = 0; j4 < 4; ++j4) {
    f32x4 v = *(const f32x4*)(s + j4 * 4);
#pragma unroll
    for (int e = 0; e < 4; ++e) {
      int d = dbase + j4 * 4 + e;
      int byte = d * 128 + ((kk * 2) ^ ((d & 7) << 4));
      *(u16*)((char*)VTs + byte) = f2bf(v[e]);
    }
  }
}

// ---------------- kernel 1: partial rowsums + unnormalized partial O ----------
__global__ void __launch_bounds__(256) k_sumo(
    const float* __restrict__ Q, const float* __restrict__ K,
    const float* __restrict__ V, float* __restrict__ wsRow,
    float* __restrict__ wsO) {
  __shared__ __align__(16) u16 Ks[64 * 64];
  __shared__ __align__(16) u16 VTs[64 * 64];
  __shared__ __align__(16) u16 Ps[64 * 64];

  const int t = threadIdx.x, lane = t & 63, w = t >> 6;
  const int cl = lane & 15, lg = lane >> 4;
  const int bx = blockIdx.x;
  const int qt = 63 - (bx >> 6);       // heavy first
  const int b = (bx >> 3) & 7;
  const int kc = bx & 7;
  if (kc > (qt >> 3)) return;          // chunk fully above diagonal
  const int q0 = qt * 64;

  const float* Qg = Q + ((size_t)b * S_LEN + q0) * D_DIM;
  const float* Kg = K + (size_t)b * S_LEN * D_DIM;
  const float* Vg = V + (size_t)b * S_LEN * D_DIM;

  // Q fragments direct from global
  const int qrow = w * 16 + cl;
  f32x4 qv0 = *(const f32x4*)(Qg + qrow * D_DIM + lg * 8);
  f32x4 qv1 = *(const f32x4*)(Qg + qrow * D_DIM + lg * 8 + 4);
  f32x4 qv2 = *(const f32x4*)(Qg + qrow * D_DIM + 32 + lg * 8);
  f32x4 qv3 = *(const f32x4*)(Qg + qrow * D_DIM + 32 + lg * 8 + 4);
  bf16x8 aq0 = pack8(qv0, qv1), aq1 = pack8(qv2, qv3);

  const int nt = (kc < (qt >> 3)) ? 8 : ((qt & 7) + 1);
  float psum[4] = {0.f, 0.f, 0.f, 0.f};
  f32x4 oacc[4];
#pragma unroll
  for (int dt = 0; dt < 4; ++dt) oacc[dt] = (f32x4){0.f, 0.f, 0.f, 0.f};

  for (int ct64 = 0; ct64 < nt; ++ct64) {
    const int ktg = kc * 512 + ct64 * 64;
    __syncthreads();
    stageK_fn(Ks, Kg + (size_t)ktg * D_DIM, t);
    stageV_fn(VTs, Vg + (size_t)ktg * D_DIM, t);
    __syncthreads();
    const bool maskTile = (ktg == q0);   // only the diagonal tile needs masking
#pragma unroll
    for (int ct = 0; ct < 4; ++ct) {
      int krow = ct * 16 + cl;
      int bb0 = krow * 128 + ((lg * 16) ^ ((krow & 7) << 4));
      int bb1 = krow * 128 + ((64 + lg * 16) ^ ((krow & 7) << 4));
      bf16x8 bk0 = *(const bf16x8*)((char*)Ks + bb0);
      bf16x8 bk1 = *(const bf16x8*)((char*)Ks + bb1);
      f32x4 c = {0.f, 0.f, 0.f, 0.f};
      c = __builtin_amdgcn_mfma_f32_16x16x32_bf16(aq0, bk0, c, 0, 0, 0);
      c = __builtin_amdgcn_mfma_f32_16x16x32_bf16(aq1, bk1, c, 0, 0, 0);
      int rowl = w * 16 + lg * 4;
#pragma unroll
      for (int r = 0; r < 4; ++r) {
        float e = __expf(c[r] * 0.125f);
        if (maskTile && (ct * 16 + cl) > (rowl + r)) e = 0.f;  // local col>row
        psum[r] += e;
        int pr = rowl + r;
        int byte = pr * 128 + ((((ct * 16 + cl) * 2)) ^ ((pr & 7) << 4));
        *(u16*)((char*)Ps + byte) = f2bf(e);   // unnormalized
      }
    }
    // PV: Ps rows read are same-wave-written; VTs covered by staging barrier
    {
      int prow = w * 16 + cl;
      int pb0 = prow * 128 + ((lg * 16) ^ ((prow & 7) << 4));
      int pb1 = prow * 128 + ((64 + lg * 16) ^ ((prow & 7) << 4));
      bf16x8 pa0 = *(const bf16x8*)((char*)Ps + pb0);
      bf16x8 pa1 = *(const bf16x8*)((char*)Ps + pb1);
#pragma unroll
      for (int dt = 0; dt < 4; ++dt) {
        int vrow = dt * 16 + cl;
        int vb0 = vrow * 128 + ((lg * 16) ^ ((vrow & 7) << 4));
        int vb1 = vrow * 128 + ((64 + lg * 16) ^ ((vrow & 7) << 4));
        bf16x8 v0 = *(const bf16x8*)((char*)VTs + vb0);
        bf16x8 v1 = *(const bf16x8*)((char*)VTs + vb1);
        oacc[dt] = __builtin_amdgcn_mfma_f32_16x16x32_bf16(pa0, v0, oacc[dt], 0, 0, 0);
        oacc[dt] = __builtin_amdgcn_mfma_f32_16x16x32_bf16(pa1, v1, oacc[dt], 0, 0, 0);
      }
    }
  }

  // reduce rowsums across the 16 col-lanes and store
#pragma unroll
  for (int r = 0; r < 4; ++r) {
    float s = psum[r];
    s += __shfl_xor(s, 1, 64);
    s += __shfl_xor(s, 2, 64);
    s += __shfl_xor(s, 4, 64);
    s += __shfl_xor(s, 8, 64);
    psum[r] = s;
  }
  const int slot = ((b * 64 + qt) * 8 + kc);
  if (cl == 0) {
#pragma unroll
    for (int r = 0; r < 4; ++r)
      wsRow[(size_t)slot * 64 + w * 16 + lg * 4 + r] = psum[r];
  }
  float* dstO = wsO + (size_t)slot * 4096;
#pragma unroll
  for (int dt = 0; dt < 4; ++dt)
#pragma unroll
    for (int r = 0; r < 4; ++r)
      dstO[(w * 16 + lg * 4 + r) * 64 + dt * 16 + cl] = oacc[dt][r];
}

// ---------------- kernel 2: normalized P writes, LDS-free / barrier-free -----
__global__ void __launch_bounds__(256) k_pwrite(
    const float* __restrict__ Q, const float* __restrict__ K,
    const float* __restrict__ wsRow, float* __restrict__ Pg) {
  const int t = threadIdx.x, lane = t & 63, w = t >> 6;
  const int cl = lane & 15, lg = lane >> 4;
  const int bx = blockIdx.x;
  const int qt = 63 - (bx >> 6);
  const int b = (bx >> 3) & 7;
  const int kc = bx & 7;
  const int q0 = qt * 64;
  float* PgB = Pg + ((size_t)b * S_LEN + q0) * S_LEN + kc * 512;

  if (kc > (qt >> 3)) {  // fully above diagonal: pure zero-fill, 128KB
    f32x4 z = {0.f, 0.f, 0.f, 0.f};
    for (int idx = t; idx < 8192; idx += 256)
      *((f32x4*)(PgB + (size_t)(idx >> 7) * S_LEN) + (idx & 127)) = z;
    return;
  }

  const int nt = (kc < (qt >> 3)) ? 8 : ((qt & 7) + 1);
  if (nt < 8) {  // zero-fill the tail columns of a straddling chunk
    int zc4 = (8 - nt) * 16;
    f32x4 z = {0.f, 0.f, 0.f, 0.f};
    for (int r = 0; r < 64; ++r) {
      f32x4* rowp = (f32x4*)(PgB + (size_t)r * S_LEN + nt * 64);
      for (int c = t; c < zc4; c += 256) rowp[c] = z;
    }
  }

  // 1/l for this lane's q-row (one row per lane now)
  const int nkc = (qt >> 3) + 1;
  const float* rowbase = wsRow + (size_t)(b * 64 + qt) * 8 * 64;
  const int qrl = w * 16 + cl;         // this lane's q-row within the tile
  float ls = 0.f;
  for (int k2 = 0; k2 < nkc; ++k2) ls += rowbase[k2 * 64 + qrl];
  const float rl = 1.0f / ls;

  const float* Qg = Q + ((size_t)b * S_LEN + q0) * D_DIM;
  const float* Kg = K + (size_t)b * S_LEN * D_DIM;

  // B-operand: Q fragments for this lane's q-row
  f32x4 qv0 = *(const f32x4*)(Qg + qrl * D_DIM + lg * 8);
  f32x4 qv1 = *(const f32x4*)(Qg + qrl * D_DIM + lg * 8 + 4);
  f32x4 qv2 = *(const f32x4*)(Qg + qrl * D_DIM + 32 + lg * 8);
  f32x4 qv3 = *(const f32x4*)(Qg + qrl * D_DIM + 32 + lg * 8 + 4);
  bf16x8 bq0 = pack8(qv0, qv1), bq1 = pack8(qv2, qv3);

  float* Prow = PgB + (size_t)qrl * S_LEN;

  for (int ct64 = 0; ct64 < nt; ++ct64) {
    const int ktg = kc * 512 + ct64 * 64;
    const float* Kt = Kg + (size_t)ktg * D_DIM;
    const bool maskTile = (ktg == q0);
#pragma unroll
    for (int ct = 0; ct < 4; ++ct) {
      // A-operand: K fragment, rows = k-values ct*16+cl, direct from global
      const float* Kr = Kt + (ct * 16 + cl) * D_DIM;
      f32x4 k0 = *(const f32x4*)(Kr + lg * 8);
      f32x4 k1 = *(const f32x4*)(Kr + lg * 8 + 4);
      f32x4 k2v = *(const f32x4*)(Kr + 32 + lg * 8);
      f32x4 k3 = *(const f32x4*)(Kr + 32 + lg * 8 + 4);
      bf16x8 ak0 = pack8(k0, k1), ak1 = pack8(k2v, k3);
      // Swapped QK^T: D[k][q]; lane -> q = cl (col), k = lg*4+r (row)
      f32x4 c = {0.f, 0.f, 0.f, 0.f};
      c = __builtin_amdgcn_mfma_f32_16x16x32_bf16(ak0, bq0, c, 0, 0, 0);
      c = __builtin_amdgcn_mfma_f32_16x16x32_bf16(ak1, bq1, c, 0, 0, 0);
      f32x4 p;
#pragma unroll
      for (int r = 0; r < 4; ++r) {
        float e = __expf(c[r] * 0.125f);
        if (maskTile && (ct * 16 + lg * 4 + r) > qrl) e = 0.f;  // local k > local q
        p[r] = e * rl;
      }
      // 4 consecutive k-cols of this lane's P row -> one dwordx4 store
      *(f32x4*)(Prow + ct64 * 64 + ct * 16 + lg * 4) = p;
    }
  }
}

// ---------------- kernel 3: reduce O partials, scale by 1/l -------------------
__global__ void __launch_bounds__(256) k_ored(
    const float* __restrict__ wsRow, const float* __restrict__ wsO,
    float* __restrict__ Og) {
  __shared__ float linv[64];
  const int bx = blockIdx.x;
  const int b = bx & 7, qt = bx >> 3;
  const int nkc = (qt >> 3) + 1;
  const int t = threadIdx.x;
  const float* rowbase = wsRow + (size_t)(b * 64 + qt) * 8 * 64;
  if (t < 64) {
    float s = 0.f;
    for (int k2 = 0; k2 < nkc; ++k2) s += rowbase[k2 * 64 + t];
    linv[t] = 1.0f / s;
  }
  __syncthreads();
  const f32x4* src = (const f32x4*)(wsO + (size_t)(b * 64 + qt) * 8 * 4096);
  f32x4* dst = (f32x4*)(Og + ((size_t)b * S_LEN + qt * 64) * D_DIM);
  for (int i = t; i < 1024; i += 256) {
    f32x4 s = {0.f, 0.f, 0.f, 0.f};
    for (int k2 = 0; k2 < nkc; ++k2) s += src[k2 * 1024 + i];
    float li = linv[i >> 4];
    s[0] *= li; s[1] *= li; s[2] *= li; s[3] *= li;
    dst[i] = s;
  }
}

// ---------------- round-0 fallback (used only if ws too small) ----------------
__global__ void __launch_bounds__(256) attn_kernel(
    const float* __restrict__ Q, const float* __restrict__ K,
    const float* __restrict__ V, float* __restrict__ Og,
    float* __restrict__ Pg) {
  __shared__ __align__(16) u16 Qs[64 * 64];
  __shared__ __align__(16) u16 Ks[64 * 64];
  __shared__ __align__(16) u16 VTs[64 * 64];
  __shared__ __align__(16) u16 Ps[64 * 64];

  const int t = threadIdx.x;
  const int lane = t & 63;
  const int w = t >> 6;
  const int cl = lane & 15;
  const int lg = lane >> 4;
  const int bx = blockIdx.x;
  const int b = bx & 7;
  const int qb = 63 - (bx >> 3);
  const int q0 = qb * 64;

  const float* Qg = Q + ((size_t)b * S_LEN + q0) * D_DIM;
  const float* Kg = K + (size_t)b * S_LEN * D_DIM;
  const float* Vg = V + (size_t)b * S_LEN * D_DIM;
  float* PgB = Pg + ((size_t)b * S_LEN + q0) * S_LEN;

  {
    int zc4 = (63 - qb) * 16;
    if (zc4 > 0) {
      f32x4 z = {0.f, 0.f, 0.f, 0.f};
      for (int r = 0; r < 64; ++r) {
        f32x4* rowp = (f32x4*)(PgB + (size_t)r * S_LEN + (size_t)(qb + 1) * 64);
        for (int c = t; c < zc4; c += 256) rowp[c] = z;
      }
    }
  }
  {
    int linear = t;
#pragma unroll
    for (int j = 0; j < 4; ++j, linear += 256) {
      int r = linear >> 4, cq = linear & 15;
      f32x4 v = *(const f32x4*)(Qg + r * D_DIM + cq * 4);
      unsigned lo = (unsigned)f2bf(v[0]) | ((unsigned)f2bf(v[1]) << 16);
      unsigned hi = (unsigned)f2bf(v[2]) | ((unsigned)f2bf(v[3]) << 16);
      int byte = r * 128 + ((cq * 8) ^ ((r & 7) << 4));
      *(unsigned long long*)((char*)Qs + byte) =
          (unsigned long long)lo | ((unsigned long long)hi << 32);
    }
  }
  __syncthreads();
  const int qrow = w * 16 + cl;
  bf16x8 aq0, aq1;
  {
    int b0 = qrow * 128 + ((lg * 16) ^ ((qrow & 7) << 4));
    int b1 = qrow * 128 + ((64 + lg * 16) ^ ((qrow & 7) << 4));
    aq0 = *(const bf16x8*)((char*)Qs + b0);
    aq1 = *(const bf16x8*)((char*)Qs + b1);
  }
  float psum[4] = {0.f, 0.f, 0.f, 0.f};
  for (int kt = 0; kt <= qb; ++kt) {
    __syncthreads();
    stageK_fn(Ks, Kg + (size_t)kt * 64 * D_DIM, t);
    __syncthreads();
#pragma unroll
    for (int ct = 0; ct < 4; ++ct) {
      int krow = ct * 16 + cl;
      int bb0 = krow * 128 + ((lg * 16) ^ ((krow & 7) << 4));
      int bb1 = krow * 128 + ((64 + lg * 16) ^ ((krow & 7) << 4));
      bf16x8 bk0 = *(const bf16x8*)((char*)Ks + bb0);
      bf16x8 bk1 = *(const bf16x8*)((char*)Ks + bb1);
      f32x4 c = {0.f, 0.f, 0.f, 0.f};
      c = __builtin_amdgcn_mfma_f32_16x16x32_bf16(aq0, bk0, c, 0, 0, 0);
      c = __builtin_amdgcn_mfma_f32_16x16x32_bf16(aq1, bk1, c, 0, 0, 0);
      int colg = kt * 64 + ct * 16 + cl;
      int rowbase = q0 + w * 16 + lg * 4;
#pragma unroll
      for (int r = 0; r < 4; ++r) {
        float e = 0.f;
        if (colg <= rowbase + r) e = __expf(c[r] * 0.125f);
        psum[r] += e;
      }
    }
  }
  float rl[4];
#pragma unroll
  for (int r = 0; r < 4; ++r) {
    float s = psum[r];
    s += __shfl_xor(s, 1, 64);
    s += __shfl_xor(s, 2, 64);
    s += __shfl_xor(s, 4, 64);
    s += __shfl_xor(s, 8, 64);
    rl[r] = 1.0f / s;
  }
  f32x4 oacc[4];
#pragma unroll
  for (int dt = 0; dt < 4; ++dt) oacc[dt] = (f32x4){0.f, 0.f, 0.f, 0.f};
  for (int kt = 0; kt <= qb; ++kt) {
    __syncthreads();
    stageK_fn(Ks, Kg + (size_t)kt * 64 * D_DIM, t);
    stageV_fn(VTs, Vg + (size_t)kt * 64 * D_DIM, t);
    __syncthreads();
#pragma unroll
    for (int ct = 0; ct < 4; ++ct) {
      int krow = ct * 16 + cl;
      int bb0 = krow * 128 + ((lg * 16) ^ ((krow & 7) << 4));
      int bb1 = krow * 128 + ((64 + lg * 16) ^ ((krow & 7) << 4));
      bf16x8 bk0 = *(const bf16x8*)((char*)Ks + bb0);
      bf16x8 bk1 = *(const bf16x8*)((char*)Ks + bb1);
      f32x4 c = {0.f, 0.f, 0.f, 0.f};
      c = __builtin_amdgcn_mfma_f32_16x16x32_bf16(aq0, bk0, c, 0, 0, 0);
      c = __builtin_amdgcn_mfma_f32_16x16x32_bf16(aq1, bk1, c, 0, 0, 0);
      int colg = kt * 64 + ct * 16 + cl;
      int rowl = w * 16 + lg * 4;
#pragma unroll
      for (int r = 0; r < 4; ++r) {
        float e = 0.f;
        if (colg <= q0 + rowl + r) e = __expf(c[r] * 0.125f);
        float p = e * rl[r];
        int pr = rowl + r;
        int byte = pr * 128 + ((((ct * 16 + cl) * 2)) ^ ((pr & 7) << 4));
        *(u16*)((char*)Ps + byte) = f2bf(p);
      }
    }
    __syncthreads();
    {
      int prow = w * 16 + cl;
      int pb0 = prow * 128 + ((lg * 16) ^ ((prow & 7) << 4));
      int pb1 = prow * 128 + ((64 + lg * 16) ^ ((prow & 7) << 4));
      bf16x8 pa0 = *(const bf16x8*)((char*)Ps + pb0);
      bf16x8 pa1 = *(const bf16x8*)((char*)Ps + pb1);
#pragma unroll
      for (int dt = 0; dt < 4; ++dt) {
        int vrow = dt * 16 + cl;
        int vb0 = vrow * 128 + ((lg * 16) ^ ((vrow & 7) << 4));
        int vb1 = vrow * 128 + ((64 + lg * 16) ^ ((vrow & 7) << 4));
        bf16x8 v0 = *(const bf16x8*)((char*)VTs + vb0);
        bf16x8 v1 = *(const bf16x8*)((char*)VTs + vb1);
        oacc[dt] = __builtin_amdgcn_mfma_f32_16x16x32_bf16(pa0, v0, oacc[dt], 0, 0, 0);
        oacc[dt] = __builtin_amdgcn_mfma_f32_16x16x32_bf16(pa1, v1, oacc[dt], 0, 0, 0);
      }
    }
#pragma unroll
    for (int j = 0; j < 2; ++j) {
      int idx = j * 256 + t;
      int pr = idx >> 3, c8 = idx & 7;
      int byte = pr * 128 + ((c8 * 16) ^ ((pr & 7) << 4));
      bf16x8 pv = *(const bf16x8*)((char*)Ps + byte);
      f32x4 f0, f1;
#pragma unroll
      for (int e = 0; e < 4; ++e) {
        f0[e] = bf2f(pv[e]);
        f1[e] = bf2f(pv[4 + e]);
      }
      f32x4* dst = (f32x4*)(PgB + (size_t)pr * S_LEN + kt * 64 + c8 * 8);
      dst[0] = f0;
      dst[1] = f1;
    }
  }
#pragma unroll
  for (int dt = 0; dt < 4; ++dt)
#pragma unroll
    for (int r = 0; r < 4; ++r)
      Og[((size_t)b * S_LEN + q0 + w * 16 + lg * 4 + r) * D_DIM + dt * 16 + cl] =
          oacc[dt][r];
}

extern "C" void kernel_launch(void* const* d_in, const int* in_sizes, int n_in,
                              void* d_out, int out_size, void* d_ws, size_t ws_size,
                              hipStream_t stream) {
  (void)in_sizes; (void)n_in; (void)out_size;
  const float* Q = (const float*)d_in[0];
  const float* K = (const float*)d_in[1];
  const float* V = (const float*)d_in[2];
  float* Og = (float*)d_out;
  float* Pg = (float*)d_out + (size_t)8 * S_LEN * D_DIM;

  const size_t need = (WSROW_FLOATS + WSO_FLOATS) * sizeof(float);
  if (d_ws != nullptr && ws_size >= need) {
    float* wsRow = (float*)d_ws;
    float* wsO = wsRow + WSROW_FLOATS;
    hipLaunchKernelGGL(k_sumo, dim3(4096), dim3(256), 0, stream, Q, K, V, wsRow, wsO);
    hipLaunchKernelGGL(k_pwrite, dim3(4096), dim3(256), 0, stream, Q, K, wsRow, Pg);
    hipLaunchKernelGGL(k_ored, dim3(512), dim3(256), 0, stream, wsRow, wsO, Og);
  } else {
    hipLaunchKernelGGL(attn_kernel, dim3(512), dim3(256), 0, stream, Q, K, V, Og, Pg);
  }
}

// Round 4
// 265.259 us; speedup vs baseline: 1.4780x; 1.4780x over previous
//
#include <hip/hip_runtime.h>
#include <hip/hip_bf16.h>

// Causal SDPA, B=8, S=4096, D=64, fp32 in/out.
// Outputs: O [8,4096,64] then attention P [8,4096,4096], concatenated in d_out.
//
// Round 3: k_pwrite hybrid (round-2 regressed: per-wave uncoalesced K gathers +
// 4x redundant bf16 conversion on the MFMA critical path).
//  - K staged to LDS coalesced, converted ONCE per block (round-1 style),
//    DOUBLE-BUFFERED: one barrier per 64-tile, prefetch overlaps compute.
//  - Swapped QK^T kept (round-2 style): mfma(A=K_frag, B=Q_frag) -> D[k][q];
//    lane holds 4 consecutive k-cols of its q-row => register->dwordx4 store,
//    no P LDS round-trip, no second barrier.
// k_sumo / k_ored unchanged from round 1.

#define S_LEN 4096
#define D_DIM 64

typedef float f32x4 __attribute__((ext_vector_type(4)));
typedef short bf16x8 __attribute__((ext_vector_type(8)));
typedef unsigned short u16;

// ws layout (floats): wsRow [8][64][8][64] = 262144, then wsO [8][64][8][4096]
#define WSROW_FLOATS (262144)
#define WSO_FLOATS   ((size_t)8 * 64 * 8 * 4096)

__device__ __forceinline__ u16 f2bf(float f) {
  union { float f; unsigned u; } x; x.f = f;
  unsigned r = x.u + 0x7fff + ((x.u >> 16) & 1);  // RNE
  return (u16)(r >> 16);
}
__device__ __forceinline__ float bf2f(short h) {
  return __uint_as_float(((unsigned)(unsigned short)h) << 16);
}
__device__ __forceinline__ bf16x8 pack8(f32x4 a, f32x4 b) {
  bf16x8 r;
  r[0] = (short)f2bf(a[0]); r[1] = (short)f2bf(a[1]);
  r[2] = (short)f2bf(a[2]); r[3] = (short)f2bf(a[3]);
  r[4] = (short)f2bf(b[0]); r[5] = (short)f2bf(b[1]);
  r[6] = (short)f2bf(b[2]); r[7] = (short)f2bf(b[3]);
  return r;
}

__device__ __forceinline__ void stageK_fn(u16* Ks, const float* src, int t) {
  int linear = t;
#pragma unroll
  for (int j = 0; j < 4; ++j, linear += 256) {
    int r = linear >> 4, cq = linear & 15;
    f32x4 v = *(const f32x4*)(src + r * D_DIM + cq * 4);
    unsigned lo = (unsigned)f2bf(v[0]) | ((unsigned)f2bf(v[1]) << 16);
    unsigned hi = (unsigned)f2bf(v[2]) | ((unsigned)f2bf(v[3]) << 16);
    int byte = r * 128 + ((cq * 8) ^ ((r & 7) << 4));
    *(unsigned long long*)((char*)Ks + byte) =
        (unsigned long long)lo | ((unsigned long long)hi << 32);
  }
}

__device__ __forceinline__ void stageV_fn(u16* VTs, const float* src, int t) {
  int kk = t >> 2;
  int dbase = (t & 3) * 16;
  const float* s = src + (size_t)kk * D_DIM + dbase;
#pragma unroll
  for (int j4 = 0; j4 < 4; ++j4) {
    f32x4 v = *(const f32x4*)(s + j4 * 4);
#pragma unroll
    for (int e = 0; e < 4; ++e) {
      int d = dbase + j4 * 4 + e;
      int byte = d * 128 + ((kk * 2) ^ ((d & 7) << 4));
      *(u16*)((char*)VTs + byte) = f2bf(v[e]);
    }
  }
}

// ---------------- kernel 1: partial rowsums + unnormalized partial O ----------
__global__ void __launch_bounds__(256) k_sumo(
    const float* __restrict__ Q, const float* __restrict__ K,
    const float* __restrict__ V, float* __restrict__ wsRow,
    float* __restrict__ wsO) {
  __shared__ __align__(16) u16 Ks[64 * 64];
  __shared__ __align__(16) u16 VTs[64 * 64];
  __shared__ __align__(16) u16 Ps[64 * 64];

  const int t = threadIdx.x, lane = t & 63, w = t >> 6;
  const int cl = lane & 15, lg = lane >> 4;
  const int bx = blockIdx.x;
  const int qt = 63 - (bx >> 6);       // heavy first
  const int b = (bx >> 3) & 7;
  const int kc = bx & 7;
  if (kc > (qt >> 3)) return;          // chunk fully above diagonal
  const int q0 = qt * 64;

  const float* Qg = Q + ((size_t)b * S_LEN + q0) * D_DIM;
  const float* Kg = K + (size_t)b * S_LEN * D_DIM;
  const float* Vg = V + (size_t)b * S_LEN * D_DIM;

  // Q fragments direct from global
  const int qrow = w * 16 + cl;
  f32x4 qv0 = *(const f32x4*)(Qg + qrow * D_DIM + lg * 8);
  f32x4 qv1 = *(const f32x4*)(Qg + qrow * D_DIM + lg * 8 + 4);
  f32x4 qv2 = *(const f32x4*)(Qg + qrow * D_DIM + 32 + lg * 8);
  f32x4 qv3 = *(const f32x4*)(Qg + qrow * D_DIM + 32 + lg * 8 + 4);
  bf16x8 aq0 = pack8(qv0, qv1), aq1 = pack8(qv2, qv3);

  const int nt = (kc < (qt >> 3)) ? 8 : ((qt & 7) + 1);
  float psum[4] = {0.f, 0.f, 0.f, 0.f};
  f32x4 oacc[4];
#pragma unroll
  for (int dt = 0; dt < 4; ++dt) oacc[dt] = (f32x4){0.f, 0.f, 0.f, 0.f};

  for (int ct64 = 0; ct64 < nt; ++ct64) {
    const int ktg = kc * 512 + ct64 * 64;
    __syncthreads();
    stageK_fn(Ks, Kg + (size_t)ktg * D_DIM, t);
    stageV_fn(VTs, Vg + (size_t)ktg * D_DIM, t);
    __syncthreads();
    const bool maskTile = (ktg == q0);   // only the diagonal tile needs masking
#pragma unroll
    for (int ct = 0; ct < 4; ++ct) {
      int krow = ct * 16 + cl;
      int bb0 = krow * 128 + ((lg * 16) ^ ((krow & 7) << 4));
      int bb1 = krow * 128 + ((64 + lg * 16) ^ ((krow & 7) << 4));
      bf16x8 bk0 = *(const bf16x8*)((char*)Ks + bb0);
      bf16x8 bk1 = *(const bf16x8*)((char*)Ks + bb1);
      f32x4 c = {0.f, 0.f, 0.f, 0.f};
      c = __builtin_amdgcn_mfma_f32_16x16x32_bf16(aq0, bk0, c, 0, 0, 0);
      c = __builtin_amdgcn_mfma_f32_16x16x32_bf16(aq1, bk1, c, 0, 0, 0);
      int rowl = w * 16 + lg * 4;
#pragma unroll
      for (int r = 0; r < 4; ++r) {
        float e = __expf(c[r] * 0.125f);
        if (maskTile && (ct * 16 + cl) > (rowl + r)) e = 0.f;  // local col>row
        psum[r] += e;
        int pr = rowl + r;
        int byte = pr * 128 + ((((ct * 16 + cl) * 2)) ^ ((pr & 7) << 4));
        *(u16*)((char*)Ps + byte) = f2bf(e);   // unnormalized
      }
    }
    // PV: Ps rows read are same-wave-written; VTs covered by staging barrier
    {
      int prow = w * 16 + cl;
      int pb0 = prow * 128 + ((lg * 16) ^ ((prow & 7) << 4));
      int pb1 = prow * 128 + ((64 + lg * 16) ^ ((prow & 7) << 4));
      bf16x8 pa0 = *(const bf16x8*)((char*)Ps + pb0);
      bf16x8 pa1 = *(const bf16x8*)((char*)Ps + pb1);
#pragma unroll
      for (int dt = 0; dt < 4; ++dt) {
        int vrow = dt * 16 + cl;
        int vb0 = vrow * 128 + ((lg * 16) ^ ((vrow & 7) << 4));
        int vb1 = vrow * 128 + ((64 + lg * 16) ^ ((vrow & 7) << 4));
        bf16x8 v0 = *(const bf16x8*)((char*)VTs + vb0);
        bf16x8 v1 = *(const bf16x8*)((char*)VTs + vb1);
        oacc[dt] = __builtin_amdgcn_mfma_f32_16x16x32_bf16(pa0, v0, oacc[dt], 0, 0, 0);
        oacc[dt] = __builtin_amdgcn_mfma_f32_16x16x32_bf16(pa1, v1, oacc[dt], 0, 0, 0);
      }
    }
  }

  // reduce rowsums across the 16 col-lanes and store
#pragma unroll
  for (int r = 0; r < 4; ++r) {
    float s = psum[r];
    s += __shfl_xor(s, 1, 64);
    s += __shfl_xor(s, 2, 64);
    s += __shfl_xor(s, 4, 64);
    s += __shfl_xor(s, 8, 64);
    psum[r] = s;
  }
  const int slot = ((b * 64 + qt) * 8 + kc);
  if (cl == 0) {
#pragma unroll
    for (int r = 0; r < 4; ++r)
      wsRow[(size_t)slot * 64 + w * 16 + lg * 4 + r] = psum[r];
  }
  float* dstO = wsO + (size_t)slot * 4096;
#pragma unroll
  for (int dt = 0; dt < 4; ++dt)
#pragma unroll
    for (int r = 0; r < 4; ++r)
      dstO[(w * 16 + lg * 4 + r) * 64 + dt * 16 + cl] = oacc[dt][r];
}

// -------- kernel 2: normalized P writes, LDS-staged K + register stores ------
__global__ void __launch_bounds__(256) k_pwrite(
    const float* __restrict__ Q, const float* __restrict__ K,
    const float* __restrict__ wsRow, float* __restrict__ Pg) {
  __shared__ __align__(16) u16 Ks[2][64 * 64];   // double-buffered K tile (bf16)

  const int t = threadIdx.x, lane = t & 63, w = t >> 6;
  const int cl = lane & 15, lg = lane >> 4;
  const int bx = blockIdx.x;
  const int qt = 63 - (bx >> 6);
  const int b = (bx >> 3) & 7;
  const int kc = bx & 7;
  const int q0 = qt * 64;
  float* PgB = Pg + ((size_t)b * S_LEN + q0) * S_LEN + kc * 512;

  if (kc > (qt >> 3)) {  // fully above diagonal: pure zero-fill, 128KB
    f32x4 z = {0.f, 0.f, 0.f, 0.f};
    for (int idx = t; idx < 8192; idx += 256)
      *((f32x4*)(PgB + (size_t)(idx >> 7) * S_LEN) + (idx & 127)) = z;
    return;
  }

  const int nt = (kc < (qt >> 3)) ? 8 : ((qt & 7) + 1);
  if (nt < 8) {  // zero-fill the tail columns of a straddling chunk
    int zc4 = (8 - nt) * 16;
    f32x4 z = {0.f, 0.f, 0.f, 0.f};
    for (int r = 0; r < 64; ++r) {
      f32x4* rowp = (f32x4*)(PgB + (size_t)r * S_LEN + nt * 64);
      for (int c = t; c < zc4; c += 256) rowp[c] = z;
    }
  }

  // 1/l for this lane's q-row
  const int nkc = (qt >> 3) + 1;
  const float* rowbase = wsRow + (size_t)(b * 64 + qt) * 8 * 64;
  const int qrl = w * 16 + cl;
  float ls = 0.f;
  for (int k2 = 0; k2 < nkc; ++k2) ls += rowbase[k2 * 64 + qrl];
  const float rl = 1.0f / ls;

  const float* Qg = Q + ((size_t)b * S_LEN + q0) * D_DIM;
  const float* Kg = K + (size_t)b * S_LEN * D_DIM;

  // B-operand: Q fragments for this lane's q-row (convert once)
  f32x4 qv0 = *(const f32x4*)(Qg + qrl * D_DIM + lg * 8);
  f32x4 qv1 = *(const f32x4*)(Qg + qrl * D_DIM + lg * 8 + 4);
  f32x4 qv2 = *(const f32x4*)(Qg + qrl * D_DIM + 32 + lg * 8);
  f32x4 qv3 = *(const f32x4*)(Qg + qrl * D_DIM + 32 + lg * 8 + 4);
  bf16x8 bq0 = pack8(qv0, qv1), bq1 = pack8(qv2, qv3);

  float* Prow = PgB + (size_t)qrl * S_LEN;

  // prologue: stage tile 0
  stageK_fn(Ks[0], Kg + (size_t)(kc * 512) * D_DIM, t);
  __syncthreads();

  for (int ct64 = 0; ct64 < nt; ++ct64) {
    if (ct64 + 1 < nt)  // prefetch next tile into the other buffer
      stageK_fn(Ks[(ct64 + 1) & 1],
                Kg + (size_t)(kc * 512 + (ct64 + 1) * 64) * D_DIM, t);
    const u16* Kb = Ks[ct64 & 1];
    const bool maskTile = (kc * 512 + ct64 * 64 == q0);
#pragma unroll
    for (int ct = 0; ct < 4; ++ct) {
      int krow = ct * 16 + cl;
      int bb0 = krow * 128 + ((lg * 16) ^ ((krow & 7) << 4));
      int bb1 = krow * 128 + ((64 + lg * 16) ^ ((krow & 7) << 4));
      bf16x8 ak0 = *(const bf16x8*)((const char*)Kb + bb0);
      bf16x8 ak1 = *(const bf16x8*)((const char*)Kb + bb1);
      // Swapped QK^T: D[k][q]; lane -> q = cl (col), k = lg*4+r (row)
      f32x4 c = {0.f, 0.f, 0.f, 0.f};
      c = __builtin_amdgcn_mfma_f32_16x16x32_bf16(ak0, bq0, c, 0, 0, 0);
      c = __builtin_amdgcn_mfma_f32_16x16x32_bf16(ak1, bq1, c, 0, 0, 0);
      f32x4 p;
#pragma unroll
      for (int r = 0; r < 4; ++r) {
        float e = __expf(c[r] * 0.125f);
        if (maskTile && (ct * 16 + lg * 4 + r) > qrl) e = 0.f;  // local k > q
        p[r] = e * rl;
      }
      *(f32x4*)(Prow + ct64 * 64 + ct * 16 + lg * 4) = p;
    }
    __syncthreads();  // next buffer staged AND current buffer reads done
  }
}

// ---------------- kernel 3: reduce O partials, scale by 1/l -------------------
__global__ void __launch_bounds__(256) k_ored(
    const float* __restrict__ wsRow, const float* __restrict__ wsO,
    float* __restrict__ Og) {
  __shared__ float linv[64];
  const int bx = blockIdx.x;
  const int b = bx & 7, qt = bx >> 3;
  const int nkc = (qt >> 3) + 1;
  const int t = threadIdx.x;
  const float* rowbase = wsRow + (size_t)(b * 64 + qt) * 8 * 64;
  if (t < 64) {
    float s = 0.f;
    for (int k2 = 0; k2 < nkc; ++k2) s += rowbase[k2 * 64 + t];
    linv[t] = 1.0f / s;
  }
  __syncthreads();
  const f32x4* src = (const f32x4*)(wsO + (size_t)(b * 64 + qt) * 8 * 4096);
  f32x4* dst = (f32x4*)(Og + ((size_t)b * S_LEN + qt * 64) * D_DIM);
  for (int i = t; i < 1024; i += 256) {
    f32x4 s = {0.f, 0.f, 0.f, 0.f};
    for (int k2 = 0; k2 < nkc; ++k2) s += src[k2 * 1024 + i];
    float li = linv[i >> 4];
    s[0] *= li; s[1] *= li; s[2] *= li; s[3] *= li;
    dst[i] = s;
  }
}

// ---------------- round-0 fallback (used only if ws too small) ----------------
__global__ void __launch_bounds__(256) attn_kernel(
    const float* __restrict__ Q, const float* __restrict__ K,
    const float* __restrict__ V, float* __restrict__ Og,
    float* __restrict__ Pg) {
  __shared__ __align__(16) u16 Qs[64 * 64];
  __shared__ __align__(16) u16 Ks[64 * 64];
  __shared__ __align__(16) u16 VTs[64 * 64];
  __shared__ __align__(16) u16 Ps[64 * 64];

  const int t = threadIdx.x;
  const int lane = t & 63;
  const int w = t >> 6;
  const int cl = lane & 15;
  const int lg = lane >> 4;
  const int bx = blockIdx.x;
  const int b = bx & 7;
  const int qb = 63 - (bx >> 3);
  const int q0 = qb * 64;

  const float* Qg = Q + ((size_t)b * S_LEN + q0) * D_DIM;
  const float* Kg = K + (size_t)b * S_LEN * D_DIM;
  const float* Vg = V + (size_t)b * S_LEN * D_DIM;
  float* PgB = Pg + ((size_t)b * S_LEN + q0) * S_LEN;

  {
    int zc4 = (63 - qb) * 16;
    if (zc4 > 0) {
      f32x4 z = {0.f, 0.f, 0.f, 0.f};
      for (int r = 0; r < 64; ++r) {
        f32x4* rowp = (f32x4*)(PgB + (size_t)r * S_LEN + (size_t)(qb + 1) * 64);
        for (int c = t; c < zc4; c += 256) rowp[c] = z;
      }
    }
  }
  {
    int linear = t;
#pragma unroll
    for (int j = 0; j < 4; ++j, linear += 256) {
      int r = linear >> 4, cq = linear & 15;
      f32x4 v = *(const f32x4*)(Qg + r * D_DIM + cq * 4);
      unsigned lo = (unsigned)f2bf(v[0]) | ((unsigned)f2bf(v[1]) << 16);
      unsigned hi = (unsigned)f2bf(v[2]) | ((unsigned)f2bf(v[3]) << 16);
      int byte = r * 128 + ((cq * 8) ^ ((r & 7) << 4));
      *(unsigned long long*)((char*)Qs + byte) =
          (unsigned long long)lo | ((unsigned long long)hi << 32);
    }
  }
  __syncthreads();
  const int qrow = w * 16 + cl;
  bf16x8 aq0, aq1;
  {
    int b0 = qrow * 128 + ((lg * 16) ^ ((qrow & 7) << 4));
    int b1 = qrow * 128 + ((64 + lg * 16) ^ ((qrow & 7) << 4));
    aq0 = *(const bf16x8*)((char*)Qs + b0);
    aq1 = *(const bf16x8*)((char*)Qs + b1);
  }
  float psum[4] = {0.f, 0.f, 0.f, 0.f};
  for (int kt = 0; kt <= qb; ++kt) {
    __syncthreads();
    stageK_fn(Ks, Kg + (size_t)kt * 64 * D_DIM, t);
    __syncthreads();
#pragma unroll
    for (int ct = 0; ct < 4; ++ct) {
      int krow = ct * 16 + cl;
      int bb0 = krow * 128 + ((lg * 16) ^ ((krow & 7) << 4));
      int bb1 = krow * 128 + ((64 + lg * 16) ^ ((krow & 7) << 4));
      bf16x8 bk0 = *(const bf16x8*)((char*)Ks + bb0);
      bf16x8 bk1 = *(const bf16x8*)((char*)Ks + bb1);
      f32x4 c = {0.f, 0.f, 0.f, 0.f};
      c = __builtin_amdgcn_mfma_f32_16x16x32_bf16(aq0, bk0, c, 0, 0, 0);
      c = __builtin_amdgcn_mfma_f32_16x16x32_bf16(aq1, bk1, c, 0, 0, 0);
      int colg = kt * 64 + ct * 16 + cl;
      int rowbase = q0 + w * 16 + lg * 4;
#pragma unroll
      for (int r = 0; r < 4; ++r) {
        float e = 0.f;
        if (colg <= rowbase + r) e = __expf(c[r] * 0.125f);
        psum[r] += e;
      }
    }
  }
  float rl[4];
#pragma unroll
  for (int r = 0; r < 4; ++r) {
    float s = psum[r];
    s += __shfl_xor(s, 1, 64);
    s += __shfl_xor(s, 2, 64);
    s += __shfl_xor(s, 4, 64);
    s += __shfl_xor(s, 8, 64);
    rl[r] = 1.0f / s;
  }
  f32x4 oacc[4];
#pragma unroll
  for (int dt = 0; dt < 4; ++dt) oacc[dt] = (f32x4){0.f, 0.f, 0.f, 0.f};
  for (int kt = 0; kt <= qb; ++kt) {
    __syncthreads();
    stageK_fn(Ks, Kg + (size_t)kt * 64 * D_DIM, t);
    stageV_fn(VTs, Vg + (size_t)kt * 64 * D_DIM, t);
    __syncthreads();
#pragma unroll
    for (int ct = 0; ct < 4; ++ct) {
      int krow = ct * 16 + cl;
      int bb0 = krow * 128 + ((lg * 16) ^ ((krow & 7) << 4));
      int bb1 = krow * 128 + ((64 + lg * 16) ^ ((krow & 7) << 4));
      bf16x8 bk0 = *(const bf16x8*)((char*)Ks + bb0);
      bf16x8 bk1 = *(const bf16x8*)((char*)Ks + bb1);
      f32x4 c = {0.f, 0.f, 0.f, 0.f};
      c = __builtin_amdgcn_mfma_f32_16x16x32_bf16(aq0, bk0, c, 0, 0, 0);
      c = __builtin_amdgcn_mfma_f32_16x16x32_bf16(aq1, bk1, c, 0, 0, 0);
      int colg = kt * 64 + ct * 16 + cl;
      int rowl = w * 16 + lg * 4;
#pragma unroll
      for (int r = 0; r < 4; ++r) {
        float e = 0.f;
        if (colg <= q0 + rowl + r) e = __expf(c[r] * 0.125f);
        float p = e * rl[r];
        int pr = rowl + r;
        int byte = pr * 128 + ((((ct * 16 + cl) * 2)) ^ ((pr & 7) << 4));
        *(u16*)((char*)Ps + byte) = f2bf(p);
      }
    }
    __syncthreads();
    {
      int prow = w * 16 + cl;
      int pb0 = prow * 128 + ((lg * 16) ^ ((prow & 7) << 4));
      int pb1 = prow * 128 + ((64 + lg * 16) ^ ((prow & 7) << 4));
      bf16x8 pa0 = *(const bf16x8*)((char*)Ps + pb0);
      bf16x8 pa1 = *(const bf16x8*)((char*)Ps + pb1);
#pragma unroll
      for (int dt = 0; dt < 4; ++dt) {
        int vrow = dt * 16 + cl;
        int vb0 = vrow * 128 + ((lg * 16) ^ ((vrow & 7) << 4));
        int vb1 = vrow * 128 + ((64 + lg * 16) ^ ((vrow & 7) << 4));
        bf16x8 v0 = *(const bf16x8*)((char*)VTs + vb0);
        bf16x8 v1 = *(const bf16x8*)((char*)VTs + vb1);
        oacc[dt] = __builtin_amdgcn_mfma_f32_16x16x32_bf16(pa0, v0, oacc[dt], 0, 0, 0);
        oacc[dt] = __builtin_amdgcn_mfma_f32_16x16x32_bf16(pa1, v1, oacc[dt], 0, 0, 0);
      }
    }
#pragma unroll
    for (int j = 0; j < 2; ++j) {
      int idx = j * 256 + t;
      int pr = idx >> 3, c8 = idx & 7;
      int byte = pr * 128 + ((c8 * 16) ^ ((pr & 7) << 4));
      bf16x8 pv = *(const bf16x8*)((char*)Ps + byte);
      f32x4 f0, f1;
#pragma unroll
      for (int e = 0; e < 4; ++e) {
        f0[e] = bf2f(pv[e]);
        f1[e] = bf2f(pv[4 + e]);
      }
      f32x4* dst = (f32x4*)(PgB + (size_t)pr * S_LEN + kt * 64 + c8 * 8);
      dst[0] = f0;
      dst[1] = f1;
    }
  }
#pragma unroll
  for (int dt = 0; dt < 4; ++dt)
#pragma unroll
    for (int r = 0; r < 4; ++r)
      Og[((size_t)b * S_LEN + q0 + w * 16 + lg * 4 + r) * D_DIM + dt * 16 + cl] =
          oacc[dt][r];
}

extern "C" void kernel_launch(void* const* d_in, const int* in_sizes, int n_in,
                              void* d_out, int out_size, void* d_ws, size_t ws_size,
                              hipStream_t stream) {
  (void)in_sizes; (void)n_in; (void)out_size;
  const float* Q = (const float*)d_in[0];
  const float* K = (const float*)d_in[1];
  const float* V = (const float*)d_in[2];
  float* Og = (float*)d_out;
  float* Pg = (float*)d_out + (size_t)8 * S_LEN * D_DIM;

  const size_t need = (WSROW_FLOATS + WSO_FLOATS) * sizeof(float);
  if (d_ws != nullptr && ws_size >= need) {
    float* wsRow = (float*)d_ws;
    float* wsO = wsRow + WSROW_FLOATS;
    hipLaunchKernelGGL(k_sumo, dim3(4096), dim3(256), 0, stream, Q, K, V, wsRow, wsO);
    hipLaunchKernelGGL(k_pwrite, dim3(4096), dim3(256), 0, stream, Q, K, wsRow, Pg);
    hipLaunchKernelGGL(k_ored, dim3(512), dim3(256), 0, stream, wsRow, wsO, Og);
  } else {
    hipLaunchKernelGGL(attn_kernel, dim3(512), dim3(256), 0, stream, Q, K, V, Og, Pg);
  }
}

// Round 5
// 254.549 us; speedup vs baseline: 1.5401x; 1.0421x over previous
//
#include <hip/hip_runtime.h>
#include <hip/hip_bf16.h>

// Causal SDPA, B=8, S=4096, D=64, fp32 in/out.
// Outputs: O [8,4096,64] then attention P [8,4096,4096], concatenated in d_out.
//
// Round 4: k_sumo rewritten (it, not k_pwrite, dominates):
//  - swapped QK^T (mfma(K,Q), proven in r2/r3): lane owns 4 k-cols of its q-row
//    -> in-register rowsum (2 shfls total), Ps stored via 1 packed ds_write_b64
//    per subtile (was 16 scalar u16 -> bank-conflict storm).
//  - V^T staged with lane-coalesced strided loads + 2 ds_write_b128 (was 16
//    scalar u16/thread -> ~16-way conflicts, 6.4M SQ_LDS_BANK_CONFLICT in r0).
//  - T14 split staging both kernels: issue loads->regs BEFORE compute,
//    ds_write AFTER compute, one barrier/tile (r3's "dbuf" had no overlap:
//    load->ds_write->compute program order stalls on vmcnt before MFMA).
// k_ored unchanged.

#define S_LEN 4096
#define D_DIM 64

typedef float f32x4 __attribute__((ext_vector_type(4)));
typedef short bf16x8 __attribute__((ext_vector_type(8)));
typedef unsigned short u16;
typedef unsigned long long u64;

// ws layout (floats): wsRow [8][64][8][64] = 262144, then wsO [8][64][8][4096]
#define WSROW_FLOATS (262144)
#define WSO_FLOATS   ((size_t)8 * 64 * 8 * 4096)

__device__ __forceinline__ u16 f2bf(float f) {
  union { float f; unsigned u; } x; x.f = f;
  unsigned r = x.u + 0x7fff + ((x.u >> 16) & 1);  // RNE
  return (u16)(r >> 16);
}
__device__ __forceinline__ float bf2f(short h) {
  return __uint_as_float(((unsigned)(unsigned short)h) << 16);
}
__device__ __forceinline__ bf16x8 pack8(f32x4 a, f32x4 b) {
  bf16x8 r;
  r[0] = (short)f2bf(a[0]); r[1] = (short)f2bf(a[1]);
  r[2] = (short)f2bf(a[2]); r[3] = (short)f2bf(a[3]);
  r[4] = (short)f2bf(b[0]); r[5] = (short)f2bf(b[1]);
  r[6] = (short)f2bf(b[2]); r[7] = (short)f2bf(b[3]);
  return r;
}
__device__ __forceinline__ unsigned pk2(float a, float b) {
  return (unsigned)f2bf(a) | ((unsigned)f2bf(b) << 16);
}

// legacy combined stage (fallback kernel only)
__device__ __forceinline__ void stageK_fn(u16* Ks, const float* src, int t) {
  int linear = t;
#pragma unroll
  for (int j = 0; j < 4; ++j, linear += 256) {
    int r = linear >> 4, cq = linear & 15;
    f32x4 v = *(const f32x4*)(src + r * D_DIM + cq * 4);
    int byte = r * 128 + ((cq * 8) ^ ((r & 7) << 4));
    *(u64*)((char*)Ks + byte) =
        (u64)pk2(v[0], v[1]) | ((u64)pk2(v[2], v[3]) << 32);
  }
}
__device__ __forceinline__ void stageV_fn(u16* VTs, const float* src, int t) {
  int kk = t >> 2;
  int dbase = (t & 3) * 16;
  const float* s = src + (size_t)kk * D_DIM + dbase;
#pragma unroll
  for (int j4 = 0; j4 < 4; ++j4) {
    f32x4 v = *(const f32x4*)(s + j4 * 4);
#pragma unroll
    for (int e = 0; e < 4; ++e) {
      int d = dbase + j4 * 4 + e;
      int byte = d * 128 + ((kk * 2) ^ ((d & 7) << 4));
      *(u16*)((char*)VTs + byte) = f2bf(v[e]);
    }
  }
}

// ---------------- kernel 1: partial rowsums + unnormalized partial O ----------
__global__ void __launch_bounds__(256) k_sumo(
    const float* __restrict__ Q, const float* __restrict__ K,
    const float* __restrict__ V, float* __restrict__ wsRow,
    float* __restrict__ wsO) {
  __shared__ __align__(16) u16 Ks[2][64 * 64];
  __shared__ __align__(16) u16 VTs[2][64 * 64];
  __shared__ __align__(16) u16 Ps[64 * 64];   // per-wave-private rows

  const int t = threadIdx.x, lane = t & 63, w = t >> 6;
  const int cl = lane & 15, lg = lane >> 4;
  const int bx = blockIdx.x;
  const int qt = 63 - (bx >> 6);       // heavy first
  const int b = (bx >> 3) & 7;
  const int kc = bx & 7;
  if (kc > (qt >> 3)) return;
  const int q0 = qt * 64;

  const float* Qg = Q + ((size_t)b * S_LEN + q0) * D_DIM;
  const float* Kg = K + (size_t)b * S_LEN * D_DIM;
  const float* Vg = V + (size_t)b * S_LEN * D_DIM;

  // B-operand: Q fragment for this lane's q-row (row = w*16+cl), convert once
  const int qrl = w * 16 + cl;
  f32x4 qv0 = *(const f32x4*)(Qg + qrl * D_DIM + lg * 8);
  f32x4 qv1 = *(const f32x4*)(Qg + qrl * D_DIM + lg * 8 + 4);
  f32x4 qv2 = *(const f32x4*)(Qg + qrl * D_DIM + 32 + lg * 8);
  f32x4 qv3 = *(const f32x4*)(Qg + qrl * D_DIM + 32 + lg * 8 + 4);
  bf16x8 bq0 = pack8(qv0, qv1), bq1 = pack8(qv2, qv3);

  const int nt = (kc < (qt >> 3)) ? 8 : ((qt & 7) + 1);

  // staging registers (T14 split)
  f32x4 kreg[4];
  float vreg[16];
  const int vd = t & 63, vq = t >> 6;   // V loader: lane=d (coalesced), quarter=k/16

  // --- staging helpers (macros to keep static indexing) ---
#define LOADK(ktg_)                                                        \
  {                                                                        \
    const float* src_ = Kg + (size_t)(ktg_)*D_DIM;                         \
    _Pragma("unroll") for (int j = 0; j < 4; ++j) {                        \
      int lin = t + j * 256, r_ = lin >> 4, cq_ = lin & 15;                \
      kreg[j] = *(const f32x4*)(src_ + r_ * D_DIM + cq_ * 4);              \
    }                                                                      \
  }
#define WRITEK(buf_)                                                       \
  {                                                                        \
    _Pragma("unroll") for (int j = 0; j < 4; ++j) {                        \
      int lin = t + j * 256, r_ = lin >> 4, cq_ = lin & 15;                \
      int byte_ = r_ * 128 + ((cq_ * 8) ^ ((r_ & 7) << 4));                \
      *(u64*)((char*)(buf_) + byte_) =                                     \
          (u64)pk2(kreg[j][0], kreg[j][1]) |                               \
          ((u64)pk2(kreg[j][2], kreg[j][3]) << 32);                        \
    }                                                                      \
  }
#define LOADV(ktg_)                                                        \
  {                                                                        \
    const float* src_ = Vg + (size_t)((ktg_) + vq * 16) * D_DIM + vd;      \
    _Pragma("unroll") for (int j = 0; j < 16; ++j)                         \
        vreg[j] = src_[j * D_DIM];                                         \
  }
#define WRITEV(buf_)                                                       \
  {                                                                        \
    uint4 a_, b_;                                                          \
    a_.x = pk2(vreg[0], vreg[1]);  a_.y = pk2(vreg[2], vreg[3]);           \
    a_.z = pk2(vreg[4], vreg[5]);  a_.w = pk2(vreg[6], vreg[7]);           \
    b_.x = pk2(vreg[8], vreg[9]);  b_.y = pk2(vreg[10], vreg[11]);         \
    b_.z = pk2(vreg[12], vreg[13]); b_.w = pk2(vreg[14], vreg[15]);        \
    int swz_ = (vd & 7) << 4;                                              \
    *(uint4*)((char*)(buf_) + vd * 128 + ((vq * 32) ^ swz_)) = a_;         \
    *(uint4*)((char*)(buf_) + vd * 128 + ((vq * 32 + 16) ^ swz_)) = b_;    \
  }

  float psum = 0.f;
  f32x4 oacc[4];
#pragma unroll
  for (int dt = 0; dt < 4; ++dt) oacc[dt] = (f32x4){0.f, 0.f, 0.f, 0.f};

  // prologue: stage tile 0 into buffer 0
  LOADK(kc * 512);
  LOADV(kc * 512);
  WRITEK(Ks[0]);
  WRITEV(VTs[0]);
  __syncthreads();

  int cur = 0;
  for (int ct64 = 0; ct64 < nt; ++ct64) {
    const int ktg = kc * 512 + ct64 * 64;
    const bool maskTile = (ktg == q0);
    const bool hasNext = (ct64 + 1 < nt);
    if (hasNext) {  // issue next-tile loads NOW; they fly under the compute
      LOADK(ktg + 64);
      LOADV(ktg + 64);
    }
    const u16* Kb = Ks[cur];
    const u16* Vb = VTs[cur];

    // ---- swapped QK^T: D[k_local=lg*4+r][q=cl]; lane owns its q-row ----
#pragma unroll
    for (int ct = 0; ct < 4; ++ct) {
      int krow = ct * 16 + cl;
      int bb0 = krow * 128 + ((lg * 16) ^ ((krow & 7) << 4));
      int bb1 = krow * 128 + ((64 + lg * 16) ^ ((krow & 7) << 4));
      bf16x8 ak0 = *(const bf16x8*)((const char*)Kb + bb0);
      bf16x8 ak1 = *(const bf16x8*)((const char*)Kb + bb1);
      f32x4 c = {0.f, 0.f, 0.f, 0.f};
      c = __builtin_amdgcn_mfma_f32_16x16x32_bf16(ak0, bq0, c, 0, 0, 0);
      c = __builtin_amdgcn_mfma_f32_16x16x32_bf16(ak1, bq1, c, 0, 0, 0);
      float e[4];
#pragma unroll
      for (int r = 0; r < 4; ++r) {
        float ev = __expf(c[r] * 0.125f);
        if (maskTile && (ct * 16 + lg * 4 + r) > qrl) ev = 0.f;
        e[r] = ev;
        psum += ev;
      }
      // one packed b64 store: Ps[q=qrl][k=ct*16+lg*4 .. +3], unnormalized
      int pbyte = qrl * 128 + (((ct * 32 + lg * 8)) ^ ((qrl & 7) << 4));
      *(u64*)((char*)Ps + pbyte) =
          (u64)pk2(e[0], e[1]) | ((u64)pk2(e[2], e[3]) << 32);
    }

    // ---- PV (standard operands; Ps rows are same-wave-written) ----
    {
      int pb0 = qrl * 128 + ((lg * 16) ^ ((qrl & 7) << 4));
      int pb1 = qrl * 128 + ((64 + lg * 16) ^ ((qrl & 7) << 4));
      bf16x8 pa0 = *(const bf16x8*)((char*)Ps + pb0);
      bf16x8 pa1 = *(const bf16x8*)((char*)Ps + pb1);
#pragma unroll
      for (int dt = 0; dt < 4; ++dt) {
        int vrow = dt * 16 + cl;
        int vb0 = vrow * 128 + ((lg * 16) ^ ((vrow & 7) << 4));
        int vb1 = vrow * 128 + ((64 + lg * 16) ^ ((vrow & 7) << 4));
        bf16x8 v0 = *(const bf16x8*)((const char*)Vb + vb0);
        bf16x8 v1 = *(const bf16x8*)((const char*)Vb + vb1);
        oacc[dt] = __builtin_amdgcn_mfma_f32_16x16x32_bf16(pa0, v0, oacc[dt], 0, 0, 0);
        oacc[dt] = __builtin_amdgcn_mfma_f32_16x16x32_bf16(pa1, v1, oacc[dt], 0, 0, 0);
      }
    }

    if (hasNext) {  // write prefetched tile AFTER compute (T14)
      WRITEK(Ks[cur ^ 1]);
      WRITEV(VTs[cur ^ 1]);
    }
    __syncthreads();
    cur ^= 1;
  }

  // rowsum: lane holds partial over its lg's k-subset -> reduce across lg
  psum += __shfl_xor(psum, 16, 64);
  psum += __shfl_xor(psum, 32, 64);
  const int slot = ((b * 64 + qt) * 8 + kc);
  if (lg == 0) wsRow[(size_t)slot * 64 + qrl] = psum;

  float* dstO = wsO + (size_t)slot * 4096;
#pragma unroll
  for (int dt = 0; dt < 4; ++dt)
#pragma unroll
    for (int r = 0; r < 4; ++r)
      dstO[(w * 16 + lg * 4 + r) * 64 + dt * 16 + cl] = oacc[dt][r];
#undef LOADK
#undef WRITEK
#undef LOADV
#undef WRITEV
}

// -------- kernel 2: normalized P writes, split-staged K + register stores ----
__global__ void __launch_bounds__(256) k_pwrite(
    const float* __restrict__ Q, const float* __restrict__ K,
    const float* __restrict__ wsRow, float* __restrict__ Pg) {
  __shared__ __align__(16) u16 Ks[2][64 * 64];

  const int t = threadIdx.x, lane = t & 63, w = t >> 6;
  const int cl = lane & 15, lg = lane >> 4;
  const int bx = blockIdx.x;
  const int qt = 63 - (bx >> 6);
  const int b = (bx >> 3) & 7;
  const int kc = bx & 7;
  const int q0 = qt * 64;
  float* PgB = Pg + ((size_t)b * S_LEN + q0) * S_LEN + kc * 512;

  if (kc > (qt >> 3)) {  // fully above diagonal: pure zero-fill, 128KB
    f32x4 z = {0.f, 0.f, 0.f, 0.f};
    for (int idx = t; idx < 8192; idx += 256)
      *((f32x4*)(PgB + (size_t)(idx >> 7) * S_LEN) + (idx & 127)) = z;
    return;
  }

  const int nt = (kc < (qt >> 3)) ? 8 : ((qt & 7) + 1);
  if (nt < 8) {  // zero-fill the tail columns of a straddling chunk
    int zc4 = (8 - nt) * 16;
    f32x4 z = {0.f, 0.f, 0.f, 0.f};
    for (int r = 0; r < 64; ++r) {
      f32x4* rowp = (f32x4*)(PgB + (size_t)r * S_LEN + nt * 64);
      for (int c = t; c < zc4; c += 256) rowp[c] = z;
    }
  }

  // 1/l for this lane's q-row
  const int nkc = (qt >> 3) + 1;
  const float* rowbase = wsRow + (size_t)(b * 64 + qt) * 8 * 64;
  const int qrl = w * 16 + cl;
  float ls = 0.f;
  for (int k2 = 0; k2 < nkc; ++k2) ls += rowbase[k2 * 64 + qrl];
  const float rl = 1.0f / ls;

  const float* Qg = Q + ((size_t)b * S_LEN + q0) * D_DIM;
  const float* Kg = K + (size_t)b * S_LEN * D_DIM;

  f32x4 qv0 = *(const f32x4*)(Qg + qrl * D_DIM + lg * 8);
  f32x4 qv1 = *(const f32x4*)(Qg + qrl * D_DIM + lg * 8 + 4);
  f32x4 qv2 = *(const f32x4*)(Qg + qrl * D_DIM + 32 + lg * 8);
  f32x4 qv3 = *(const f32x4*)(Qg + qrl * D_DIM + 32 + lg * 8 + 4);
  bf16x8 bq0 = pack8(qv0, qv1), bq1 = pack8(qv2, qv3);

  float* Prow = PgB + (size_t)qrl * S_LEN;

  f32x4 kreg[4];
#define LOADK2(ktg_)                                                       \
  {                                                                        \
    const float* src_ = Kg + (size_t)(ktg_)*D_DIM;                         \
    _Pragma("unroll") for (int j = 0; j < 4; ++j) {                        \
      int lin = t + j * 256, r_ = lin >> 4, cq_ = lin & 15;                \
      kreg[j] = *(const f32x4*)(src_ + r_ * D_DIM + cq_ * 4);              \
    }                                                                      \
  }
#define WRITEK2(buf_)                                                      \
  {                                                                        \
    _Pragma("unroll") for (int j = 0; j < 4; ++j) {                        \
      int lin = t + j * 256, r_ = lin >> 4, cq_ = lin & 15;                \
      int byte_ = r_ * 128 + ((cq_ * 8) ^ ((r_ & 7) << 4));                \
      *(u64*)((char*)(buf_) + byte_) =                                     \
          (u64)pk2(kreg[j][0], kreg[j][1]) |                               \
          ((u64)pk2(kreg[j][2], kreg[j][3]) << 32);                        \
    }                                                                      \
  }

  LOADK2(kc * 512);
  WRITEK2(Ks[0]);
  __syncthreads();

  int cur = 0;
  for (int ct64 = 0; ct64 < nt; ++ct64) {
    const bool hasNext = (ct64 + 1 < nt);
    if (hasNext) LOADK2(kc * 512 + (ct64 + 1) * 64);
    const u16* Kb = Ks[cur];
    const bool maskTile = (kc * 512 + ct64 * 64 == q0);
#pragma unroll
    for (int ct = 0; ct < 4; ++ct) {
      int krow = ct * 16 + cl;
      int bb0 = krow * 128 + ((lg * 16) ^ ((krow & 7) << 4));
      int bb1 = krow * 128 + ((64 + lg * 16) ^ ((krow & 7) << 4));
      bf16x8 ak0 = *(const bf16x8*)((const char*)Kb + bb0);
      bf16x8 ak1 = *(const bf16x8*)((const char*)Kb + bb1);
      f32x4 c = {0.f, 0.f, 0.f, 0.f};
      c = __builtin_amdgcn_mfma_f32_16x16x32_bf16(ak0, bq0, c, 0, 0, 0);
      c = __builtin_amdgcn_mfma_f32_16x16x32_bf16(ak1, bq1, c, 0, 0, 0);
      f32x4 p;
#pragma unroll
      for (int r = 0; r < 4; ++r) {
        float e = __expf(c[r] * 0.125f);
        if (maskTile && (ct * 16 + lg * 4 + r) > qrl) e = 0.f;
        p[r] = e * rl;
      }
      *(f32x4*)(Prow + ct64 * 64 + ct * 16 + lg * 4) = p;
    }
    if (hasNext) WRITEK2(Ks[cur ^ 1]);
    __syncthreads();
    cur ^= 1;
  }
#undef LOADK2
#undef WRITEK2
}

// ---------------- kernel 3: reduce O partials, scale by 1/l -------------------
__global__ void __launch_bounds__(256) k_ored(
    const float* __restrict__ wsRow, const float* __restrict__ wsO,
    float* __restrict__ Og) {
  __shared__ float linv[64];
  const int bx = blockIdx.x;
  const int b = bx & 7, qt = bx >> 3;
  const int nkc = (qt >> 3) + 1;
  const int t = threadIdx.x;
  const float* rowbase = wsRow + (size_t)(b * 64 + qt) * 8 * 64;
  if (t < 64) {
    float s = 0.f;
    for (int k2 = 0; k2 < nkc; ++k2) s += rowbase[k2 * 64 + t];
    linv[t] = 1.0f / s;
  }
  __syncthreads();
  const f32x4* src = (const f32x4*)(wsO + (size_t)(b * 64 + qt) * 8 * 4096);
  f32x4* dst = (f32x4*)(Og + ((size_t)b * S_LEN + qt * 64) * D_DIM);
  for (int i = t; i < 1024; i += 256) {
    f32x4 s = {0.f, 0.f, 0.f, 0.f};
    for (int k2 = 0; k2 < nkc; ++k2) s += src[k2 * 1024 + i];
    float li = linv[i >> 4];
    s[0] *= li; s[1] *= li; s[2] *= li; s[3] *= li;
    dst[i] = s;
  }
}

// ---------------- round-0 fallback (used only if ws too small) ----------------
__global__ void __launch_bounds__(256) attn_kernel(
    const float* __restrict__ Q, const float* __restrict__ K,
    const float* __restrict__ V, float* __restrict__ Og,
    float* __restrict__ Pg) {
  __shared__ __align__(16) u16 Qs[64 * 64];
  __shared__ __align__(16) u16 Ksh[64 * 64];
  __shared__ __align__(16) u16 VTs[64 * 64];
  __shared__ __align__(16) u16 Ps[64 * 64];

  const int t = threadIdx.x;
  const int lane = t & 63;
  const int w = t >> 6;
  const int cl = lane & 15;
  const int lg = lane >> 4;
  const int bx = blockIdx.x;
  const int b = bx & 7;
  const int qb = 63 - (bx >> 3);
  const int q0 = qb * 64;

  const float* Qg = Q + ((size_t)b * S_LEN + q0) * D_DIM;
  const float* Kg = K + (size_t)b * S_LEN * D_DIM;
  const float* Vg = V + (size_t)b * S_LEN * D_DIM;
  float* PgB = Pg + ((size_t)b * S_LEN + q0) * S_LEN;

  {
    int zc4 = (63 - qb) * 16;
    if (zc4 > 0) {
      f32x4 z = {0.f, 0.f, 0.f, 0.f};
      for (int r = 0; r < 64; ++r) {
        f32x4* rowp = (f32x4*)(PgB + (size_t)r * S_LEN + (size_t)(qb + 1) * 64);
        for (int c = t; c < zc4; c += 256) rowp[c] = z;
      }
    }
  }
  stageK_fn(Qs, Qg, t);
  __syncthreads();
  const int qrow = w * 16 + cl;
  bf16x8 aq0, aq1;
  {
    int b0 = qrow * 128 + ((lg * 16) ^ ((qrow & 7) << 4));
    int b1 = qrow * 128 + ((64 + lg * 16) ^ ((qrow & 7) << 4));
    aq0 = *(const bf16x8*)((char*)Qs + b0);
    aq1 = *(const bf16x8*)((char*)Qs + b1);
  }
  float psum[4] = {0.f, 0.f, 0.f, 0.f};
  for (int kt = 0; kt <= qb; ++kt) {
    __syncthreads();
    stageK_fn(Ksh, Kg + (size_t)kt * 64 * D_DIM, t);
    __syncthreads();
#pragma unroll
    for (int ct = 0; ct < 4; ++ct) {
      int krow = ct * 16 + cl;
      int bb0 = krow * 128 + ((lg * 16) ^ ((krow & 7) << 4));
      int bb1 = krow * 128 + ((64 + lg * 16) ^ ((krow & 7) << 4));
      bf16x8 bk0 = *(const bf16x8*)((char*)Ksh + bb0);
      bf16x8 bk1 = *(const bf16x8*)((char*)Ksh + bb1);
      f32x4 c = {0.f, 0.f, 0.f, 0.f};
      c = __builtin_amdgcn_mfma_f32_16x16x32_bf16(aq0, bk0, c, 0, 0, 0);
      c = __builtin_amdgcn_mfma_f32_16x16x32_bf16(aq1, bk1, c, 0, 0, 0);
      int colg = kt * 64 + ct * 16 + cl;
      int rowbase = q0 + w * 16 + lg * 4;
#pragma unroll
      for (int r = 0; r < 4; ++r) {
        float e = 0.f;
        if (colg <= rowbase + r) e = __expf(c[r] * 0.125f);
        psum[r] += e;
      }
    }
  }
  float rl[4];
#pragma unroll
  for (int r = 0; r < 4; ++r) {
    float s = psum[r];
    s += __shfl_xor(s, 1, 64);
    s += __shfl_xor(s, 2, 64);
    s += __shfl_xor(s, 4, 64);
    s += __shfl_xor(s, 8, 64);
    rl[r] = 1.0f / s;
  }
  f32x4 oacc[4];
#pragma unroll
  for (int dt = 0; dt < 4; ++dt) oacc[dt] = (f32x4){0.f, 0.f, 0.f, 0.f};
  for (int kt = 0; kt <= qb; ++kt) {
    __syncthreads();
    stageK_fn(Ksh, Kg + (size_t)kt * 64 * D_DIM, t);
    stageV_fn(VTs, Vg + (size_t)kt * 64 * D_DIM, t);
    __syncthreads();
#pragma unroll
    for (int ct = 0; ct < 4; ++ct) {
      int krow = ct * 16 + cl;
      int bb0 = krow * 128 + ((lg * 16) ^ ((krow & 7) << 4));
      int bb1 = krow * 128 + ((64 + lg * 16) ^ ((krow & 7) << 4));
      bf16x8 bk0 = *(const bf16x8*)((char*)Ksh + bb0);
      bf16x8 bk1 = *(const bf16x8*)((char*)Ksh + bb1);
      f32x4 c = {0.f, 0.f, 0.f, 0.f};
      c = __builtin_amdgcn_mfma_f32_16x16x32_bf16(aq0, bk0, c, 0, 0, 0);
      c = __builtin_amdgcn_mfma_f32_16x16x32_bf16(aq1, bk1, c, 0, 0, 0);
      int colg = kt * 64 + ct * 16 + cl;
      int rowl = w * 16 + lg * 4;
#pragma unroll
      for (int r = 0; r < 4; ++r) {
        float e = 0.f;
        if (colg <= q0 + rowl + r) e = __expf(c[r] * 0.125f);
        float p = e * rl[r];
        int pr = rowl + r;
        int byte = pr * 128 + ((((ct * 16 + cl) * 2)) ^ ((pr & 7) << 4));
        *(u16*)((char*)Ps + byte) = f2bf(p);
      }
    }
    __syncthreads();
    {
      int prow = w * 16 + cl;
      int pb0 = prow * 128 + ((lg * 16) ^ ((prow & 7) << 4));
      int pb1 = prow * 128 + ((64 + lg * 16) ^ ((prow & 7) << 4));
      bf16x8 pa0 = *(const bf16x8*)((char*)Ps + pb0);
      bf16x8 pa1 = *(const bf16x8*)((char*)Ps + pb1);
#pragma unroll
      for (int dt = 0; dt < 4; ++dt) {
        int vrow = dt * 16 + cl;
        int vb0 = vrow * 128 + ((lg * 16) ^ ((vrow & 7) << 4));
        int vb1 = vrow * 128 + ((64 + lg * 16) ^ ((vrow & 7) << 4));
        bf16x8 v0 = *(const bf16x8*)((char*)VTs + vb0);
        bf16x8 v1 = *(const bf16x8*)((char*)VTs + vb1);
        oacc[dt] = __builtin_amdgcn_mfma_f32_16x16x32_bf16(pa0, v0, oacc[dt], 0, 0, 0);
        oacc[dt] = __builtin_amdgcn_mfma_f32_16x16x32_bf16(pa1, v1, oacc[dt], 0, 0, 0);
      }
    }
#pragma unroll
    for (int j = 0; j < 2; ++j) {
      int idx = j * 256 + t;
      int pr = idx >> 3, c8 = idx & 7;
      int byte = pr * 128 + ((c8 * 16) ^ ((pr & 7) << 4));
      bf16x8 pv = *(const bf16x8*)((char*)Ps + byte);
      f32x4 f0, f1;
#pragma unroll
      for (int e = 0; e < 4; ++e) {
        f0[e] = bf2f(pv[e]);
        f1[e] = bf2f(pv[4 + e]);
      }
      f32x4* dst = (f32x4*)(PgB + (size_t)pr * S_LEN + kt * 64 + c8 * 8);
      dst[0] = f0;
      dst[1] = f1;
    }
  }
#pragma unroll
  for (int dt = 0; dt < 4; ++dt)
#pragma unroll
    for (int r = 0; r < 4; ++r)
      Og[((size_t)b * S_LEN + q0 + w * 16 + lg * 4 + r) * D_DIM + dt * 16 + cl] =
          oacc[dt][r];
}

extern "C" void kernel_launch(void* const* d_in, const int* in_sizes, int n_in,
                              void* d_out, int out_size, void* d_ws, size_t ws_size,
                              hipStream_t stream) {
  (void)in_sizes; (void)n_in; (void)out_size;
  const float* Q = (const float*)d_in[0];
  const float* K = (const float*)d_in[1];
  const float* V = (const float*)d_in[2];
  float* Og = (float*)d_out;
  float* Pg = (float*)d_out + (size_t)8 * S_LEN * D_DIM;

  const size_t need = (WSROW_FLOATS + WSO_FLOATS) * sizeof(float);
  if (d_ws != nullptr && ws_size >= need) {
    float* wsRow = (float*)d_ws;
    float* wsO = wsRow + WSROW_FLOATS;
    hipLaunchKernelGGL(k_sumo, dim3(4096), dim3(256), 0, stream, Q, K, V, wsRow, wsO);
    hipLaunchKernelGGL(k_pwrite, dim3(4096), dim3(256), 0, stream, Q, K, wsRow, Pg);
    hipLaunchKernelGGL(k_ored, dim3(512), dim3(256), 0, stream, wsRow, wsO, Og);
  } else {
    hipLaunchKernelGGL(attn_kernel, dim3(512), dim3(256), 0, stream, Q, K, V, Og, Pg);
  }
}

// Round 6
// 234.238 us; speedup vs baseline: 1.6737x; 1.0867x over previous
//
#include <hip/hip_runtime.h>
#include <hip/hip_bf16.h>

// Causal SDPA, B=8, S=4096, D=64, fp32 in/out.
// Outputs: O [8,4096,64] then attention P [8,4096,4096], concatenated in d_out.
//
// Round 5: rebalance the serial 3-kernel pipeline (r4 showed k_sumo micro-opts
// are neutral; the removable cost is PV living in the latency-bound kernel and
// QK^T running twice with full staging):
//  k_rowsum   : QK^T(swapped)+exp+rowsum ONLY (no V / Ps / wsO) -> wsRow
//  k_pwrite_pv: normalize P, stream P writes, AND do PV with normalized P
//               (Ps LDS same-wave path + V^T staging, both proven in r4);
//               writes normalized O partials -> wsO
//  k_ored     : pure sum of <=8 partials -> O (no scaling)
// Zero-fill overlapped with tile-0 staging loads in k_pwrite_pv.

#define S_LEN 4096
#define D_DIM 64

typedef float f32x4 __attribute__((ext_vector_type(4)));
typedef short bf16x8 __attribute__((ext_vector_type(8)));
typedef unsigned short u16;
typedef unsigned long long u64;

// ws layout (floats): wsRow [8][64][8][64] = 262144, then wsO [8][64][8][4096]
#define WSROW_FLOATS (262144)
#define WSO_FLOATS   ((size_t)8 * 64 * 8 * 4096)

__device__ __forceinline__ u16 f2bf(float f) {
  union { float f; unsigned u; } x; x.f = f;
  unsigned r = x.u + 0x7fff + ((x.u >> 16) & 1);  // RNE
  return (u16)(r >> 16);
}
__device__ __forceinline__ float bf2f(short h) {
  return __uint_as_float(((unsigned)(unsigned short)h) << 16);
}
__device__ __forceinline__ bf16x8 pack8(f32x4 a, f32x4 b) {
  bf16x8 r;
  r[0] = (short)f2bf(a[0]); r[1] = (short)f2bf(a[1]);
  r[2] = (short)f2bf(a[2]); r[3] = (short)f2bf(a[3]);
  r[4] = (short)f2bf(b[0]); r[5] = (short)f2bf(b[1]);
  r[6] = (short)f2bf(b[2]); r[7] = (short)f2bf(b[3]);
  return r;
}
__device__ __forceinline__ unsigned pk2(float a, float b) {
  return (unsigned)f2bf(a) | ((unsigned)f2bf(b) << 16);
}

// legacy combined stage (fallback kernel only)
__device__ __forceinline__ void stageK_fn(u16* Ks, const float* src, int t) {
  int linear = t;
#pragma unroll
  for (int j = 0; j < 4; ++j, linear += 256) {
    int r = linear >> 4, cq = linear & 15;
    f32x4 v = *(const f32x4*)(src + r * D_DIM + cq * 4);
    int byte = r * 128 + ((cq * 8) ^ ((r & 7) << 4));
    *(u64*)((char*)Ks + byte) =
        (u64)pk2(v[0], v[1]) | ((u64)pk2(v[2], v[3]) << 32);
  }
}
__device__ __forceinline__ void stageV_fn(u16* VTs, const float* src, int t) {
  int kk = t >> 2;
  int dbase = (t & 3) * 16;
  const float* s = src + (size_t)kk * D_DIM + dbase;
#pragma unroll
  for (int j4 = 0; j4 < 4; ++j4) {
    f32x4 v = *(const f32x4*)(s + j4 * 4);
#pragma unroll
    for (int e = 0; e < 4; ++e) {
      int d = dbase + j4 * 4 + e;
      int byte = d * 128 + ((kk * 2) ^ ((d & 7) << 4));
      *(u16*)((char*)VTs + byte) = f2bf(v[e]);
    }
  }
}

// staging macros (shared by the two main kernels)
#define LOADK_M(ktg_)                                                      \
  {                                                                        \
    const float* src_ = Kg + (size_t)(ktg_)*D_DIM;                         \
    _Pragma("unroll") for (int j = 0; j < 4; ++j) {                        \
      int lin = t + j * 256, r_ = lin >> 4, cq_ = lin & 15;                \
      kreg[j] = *(const f32x4*)(src_ + r_ * D_DIM + cq_ * 4);              \
    }                                                                      \
  }
#define WRITEK_M(buf_)                                                     \
  {                                                                        \
    _Pragma("unroll") for (int j = 0; j < 4; ++j) {                        \
      int lin = t + j * 256, r_ = lin >> 4, cq_ = lin & 15;                \
      int byte_ = r_ * 128 + ((cq_ * 8) ^ ((r_ & 7) << 4));                \
      *(u64*)((char*)(buf_) + byte_) =                                     \
          (u64)pk2(kreg[j][0], kreg[j][1]) |                               \
          ((u64)pk2(kreg[j][2], kreg[j][3]) << 32);                        \
    }                                                                      \
  }
#define LOADV_M(ktg_)                                                      \
  {                                                                        \
    const float* src_ = Vg + (size_t)((ktg_) + vq * 16) * D_DIM + vd;      \
    _Pragma("unroll") for (int j = 0; j < 16; ++j)                         \
        vreg[j] = src_[j * D_DIM];                                         \
  }
#define WRITEV_M(buf_)                                                     \
  {                                                                        \
    uint4 a_, b_;                                                          \
    a_.x = pk2(vreg[0], vreg[1]);  a_.y = pk2(vreg[2], vreg[3]);           \
    a_.z = pk2(vreg[4], vreg[5]);  a_.w = pk2(vreg[6], vreg[7]);           \
    b_.x = pk2(vreg[8], vreg[9]);  b_.y = pk2(vreg[10], vreg[11]);         \
    b_.z = pk2(vreg[12], vreg[13]); b_.w = pk2(vreg[14], vreg[15]);        \
    int swz_ = (vd & 7) << 4;                                              \
    *(uint4*)((char*)(buf_) + vd * 128 + ((vq * 32) ^ swz_)) = a_;         \
    *(uint4*)((char*)(buf_) + vd * 128 + ((vq * 32 + 16) ^ swz_)) = b_;    \
  }

// ---------------- kernel 1: partial rowsums only ------------------------------
__global__ void __launch_bounds__(256) k_rowsum(
    const float* __restrict__ Q, const float* __restrict__ K,
    float* __restrict__ wsRow) {
  __shared__ __align__(16) u16 Ks[2][64 * 64];

  const int t = threadIdx.x, lane = t & 63, w = t >> 6;
  const int cl = lane & 15, lg = lane >> 4;
  const int bx = blockIdx.x;
  const int qt = 63 - (bx >> 6);       // heavy first
  const int b = (bx >> 3) & 7;
  const int kc = bx & 7;
  if (kc > (qt >> 3)) return;
  const int q0 = qt * 64;

  const float* Qg = Q + ((size_t)b * S_LEN + q0) * D_DIM;
  const float* Kg = K + (size_t)b * S_LEN * D_DIM;

  f32x4 kreg[4];
  LOADK_M(kc * 512);   // tile-0 loads in flight

  const int qrl = w * 16 + cl;
  f32x4 qv0 = *(const f32x4*)(Qg + qrl * D_DIM + lg * 8);
  f32x4 qv1 = *(const f32x4*)(Qg + qrl * D_DIM + lg * 8 + 4);
  f32x4 qv2 = *(const f32x4*)(Qg + qrl * D_DIM + 32 + lg * 8);
  f32x4 qv3 = *(const f32x4*)(Qg + qrl * D_DIM + 32 + lg * 8 + 4);
  bf16x8 bq0 = pack8(qv0, qv1), bq1 = pack8(qv2, qv3);

  const int nt = (kc < (qt >> 3)) ? 8 : ((qt & 7) + 1);

  WRITEK_M(Ks[0]);
  __syncthreads();

  float psum = 0.f;
  int cur = 0;
  for (int ct64 = 0; ct64 < nt; ++ct64) {
    const int ktg = kc * 512 + ct64 * 64;
    const bool maskTile = (ktg == q0);
    const bool hasNext = (ct64 + 1 < nt);
    if (hasNext) LOADK_M(ktg + 64);
    const u16* Kb = Ks[cur];
#pragma unroll
    for (int ct = 0; ct < 4; ++ct) {
      int krow = ct * 16 + cl;
      int bb0 = krow * 128 + ((lg * 16) ^ ((krow & 7) << 4));
      int bb1 = krow * 128 + ((64 + lg * 16) ^ ((krow & 7) << 4));
      bf16x8 ak0 = *(const bf16x8*)((const char*)Kb + bb0);
      bf16x8 ak1 = *(const bf16x8*)((const char*)Kb + bb1);
      f32x4 c = {0.f, 0.f, 0.f, 0.f};
      c = __builtin_amdgcn_mfma_f32_16x16x32_bf16(ak0, bq0, c, 0, 0, 0);
      c = __builtin_amdgcn_mfma_f32_16x16x32_bf16(ak1, bq1, c, 0, 0, 0);
#pragma unroll
      for (int r = 0; r < 4; ++r) {
        float ev = __expf(c[r] * 0.125f);
        if (maskTile && (ct * 16 + lg * 4 + r) > qrl) ev = 0.f;
        psum += ev;
      }
    }
    if (hasNext) WRITEK_M(Ks[cur ^ 1]);
    __syncthreads();
    cur ^= 1;
  }

  psum += __shfl_xor(psum, 16, 64);
  psum += __shfl_xor(psum, 32, 64);
  const int slot = ((b * 64 + qt) * 8 + kc);
  if (lg == 0) wsRow[(size_t)slot * 64 + qrl] = psum;
}

// -------- kernel 2: P writes (normalized) + PV -> normalized O partials ------
__global__ void __launch_bounds__(256) k_pwrite_pv(
    const float* __restrict__ Q, const float* __restrict__ K,
    const float* __restrict__ V, const float* __restrict__ wsRow,
    float* __restrict__ Pg, float* __restrict__ wsO) {
  __shared__ __align__(16) u16 Ks[2][64 * 64];
  __shared__ __align__(16) u16 VTs[2][64 * 64];
  __shared__ __align__(16) u16 Ps[64 * 64];

  const int t = threadIdx.x, lane = t & 63, w = t >> 6;
  const int cl = lane & 15, lg = lane >> 4;
  const int bx = blockIdx.x;
  const int qt = 63 - (bx >> 6);
  const int b = (bx >> 3) & 7;
  const int kc = bx & 7;
  const int q0 = qt * 64;
  float* PgB = Pg + ((size_t)b * S_LEN + q0) * S_LEN + kc * 512;

  if (kc > (qt >> 3)) {  // fully above diagonal: pure zero-fill, 128KB
    f32x4 z = {0.f, 0.f, 0.f, 0.f};
    for (int idx = t; idx < 8192; idx += 256)
      *((f32x4*)(PgB + (size_t)(idx >> 7) * S_LEN) + (idx & 127)) = z;
    return;
  }

  const float* Qg = Q + ((size_t)b * S_LEN + q0) * D_DIM;
  const float* Kg = K + (size_t)b * S_LEN * D_DIM;
  const float* Vg = V + (size_t)b * S_LEN * D_DIM;

  // issue tile-0 staging loads FIRST; zero-fill + rl computation hide them
  f32x4 kreg[4];
  float vreg[16];
  const int vd = t & 63, vq = t >> 6;
  LOADK_M(kc * 512);
  LOADV_M(kc * 512);

  const int nt = (kc < (qt >> 3)) ? 8 : ((qt & 7) + 1);
  if (nt < 8) {  // zero-fill the tail columns of a straddling chunk
    int zc4 = (8 - nt) * 16;
    f32x4 z = {0.f, 0.f, 0.f, 0.f};
    for (int r = 0; r < 64; ++r) {
      f32x4* rowp = (f32x4*)(PgB + (size_t)r * S_LEN + nt * 64);
      for (int c = t; c < zc4; c += 256) rowp[c] = z;
    }
  }

  // 1/l for this lane's q-row
  const int nkc = (qt >> 3) + 1;
  const float* rowbase = wsRow + (size_t)(b * 64 + qt) * 8 * 64;
  const int qrl = w * 16 + cl;
  float ls = 0.f;
  for (int k2 = 0; k2 < nkc; ++k2) ls += rowbase[k2 * 64 + qrl];
  const float rl = 1.0f / ls;

  f32x4 qv0 = *(const f32x4*)(Qg + qrl * D_DIM + lg * 8);
  f32x4 qv1 = *(const f32x4*)(Qg + qrl * D_DIM + lg * 8 + 4);
  f32x4 qv2 = *(const f32x4*)(Qg + qrl * D_DIM + 32 + lg * 8);
  f32x4 qv3 = *(const f32x4*)(Qg + qrl * D_DIM + 32 + lg * 8 + 4);
  bf16x8 bq0 = pack8(qv0, qv1), bq1 = pack8(qv2, qv3);

  float* Prow = PgB + (size_t)qrl * S_LEN;

  WRITEK_M(Ks[0]);
  WRITEV_M(VTs[0]);
  __syncthreads();

  f32x4 oacc[4];
#pragma unroll
  for (int dt = 0; dt < 4; ++dt) oacc[dt] = (f32x4){0.f, 0.f, 0.f, 0.f};

  int cur = 0;
  for (int ct64 = 0; ct64 < nt; ++ct64) {
    const int ktg = kc * 512 + ct64 * 64;
    const bool maskTile = (ktg == q0);
    const bool hasNext = (ct64 + 1 < nt);
    if (hasNext) {  // issue next-tile loads under this tile's compute (T14)
      LOADK_M(ktg + 64);
      LOADV_M(ktg + 64);
    }
    const u16* Kb = Ks[cur];
    const u16* Vb = VTs[cur];

    // swapped QK^T: lane owns q-row qrl, 4 consecutive k per subtile
#pragma unroll
    for (int ct = 0; ct < 4; ++ct) {
      int krow = ct * 16 + cl;
      int bb0 = krow * 128 + ((lg * 16) ^ ((krow & 7) << 4));
      int bb1 = krow * 128 + ((64 + lg * 16) ^ ((krow & 7) << 4));
      bf16x8 ak0 = *(const bf16x8*)((const char*)Kb + bb0);
      bf16x8 ak1 = *(const bf16x8*)((const char*)Kb + bb1);
      f32x4 c = {0.f, 0.f, 0.f, 0.f};
      c = __builtin_amdgcn_mfma_f32_16x16x32_bf16(ak0, bq0, c, 0, 0, 0);
      c = __builtin_amdgcn_mfma_f32_16x16x32_bf16(ak1, bq1, c, 0, 0, 0);
      f32x4 p;
#pragma unroll
      for (int r = 0; r < 4; ++r) {
        float e = __expf(c[r] * 0.125f);
        if (maskTile && (ct * 16 + lg * 4 + r) > qrl) e = 0.f;
        p[r] = e * rl;
      }
      // stream normalized P: one dwordx4 per subtile
      *(f32x4*)(Prow + ct64 * 64 + ct * 16 + lg * 4) = p;
      // pack normalized P for PV (same-wave rows; proven r4 path)
      int pbyte = qrl * 128 + (((ct * 32 + lg * 8)) ^ ((qrl & 7) << 4));
      *(u64*)((char*)Ps + pbyte) =
          (u64)pk2(p[0], p[1]) | ((u64)pk2(p[2], p[3]) << 32);
    }

    // PV with normalized P -> normalized O partials
    {
      int pb0 = qrl * 128 + ((lg * 16) ^ ((qrl & 7) << 4));
      int pb1 = qrl * 128 + ((64 + lg * 16) ^ ((qrl & 7) << 4));
      bf16x8 pa0 = *(const bf16x8*)((char*)Ps + pb0);
      bf16x8 pa1 = *(const bf16x8*)((char*)Ps + pb1);
#pragma unroll
      for (int dt = 0; dt < 4; ++dt) {
        int vrow = dt * 16 + cl;
        int vb0 = vrow * 128 + ((lg * 16) ^ ((vrow & 7) << 4));
        int vb1 = vrow * 128 + ((64 + lg * 16) ^ ((vrow & 7) << 4));
        bf16x8 v0 = *(const bf16x8*)((const char*)Vb + vb0);
        bf16x8 v1 = *(const bf16x8*)((const char*)Vb + vb1);
        oacc[dt] = __builtin_amdgcn_mfma_f32_16x16x32_bf16(pa0, v0, oacc[dt], 0, 0, 0);
        oacc[dt] = __builtin_amdgcn_mfma_f32_16x16x32_bf16(pa1, v1, oacc[dt], 0, 0, 0);
      }
    }

    if (hasNext) {  // write prefetched tile AFTER compute (T14)
      WRITEK_M(Ks[cur ^ 1]);
      WRITEV_M(VTs[cur ^ 1]);
    }
    __syncthreads();
    cur ^= 1;
  }

  const int slot = ((b * 64 + qt) * 8 + kc);
  float* dstO = wsO + (size_t)slot * 4096;
#pragma unroll
  for (int dt = 0; dt < 4; ++dt)
#pragma unroll
    for (int r = 0; r < 4; ++r)
      dstO[(w * 16 + lg * 4 + r) * 64 + dt * 16 + cl] = oacc[dt][r];
}

// ---------------- kernel 3: sum O partials (already normalized) --------------
__global__ void __launch_bounds__(256) k_ored(
    const float* __restrict__ wsO, float* __restrict__ Og) {
  const int bx = blockIdx.x;
  const int b = bx & 7, qt = bx >> 3;
  const int nkc = (qt >> 3) + 1;
  const int t = threadIdx.x;
  const f32x4* src = (const f32x4*)(wsO + (size_t)(b * 64 + qt) * 8 * 4096);
  f32x4* dst = (f32x4*)(Og + ((size_t)b * S_LEN + qt * 64) * D_DIM);
  for (int i = t; i < 1024; i += 256) {
    f32x4 s = {0.f, 0.f, 0.f, 0.f};
    for (int k2 = 0; k2 < nkc; ++k2) s += src[k2 * 1024 + i];
    dst[i] = s;
  }
}

// ---------------- round-0 fallback (used only if ws too small) ----------------
__global__ void __launch_bounds__(256) attn_kernel(
    const float* __restrict__ Q, const float* __restrict__ K,
    const float* __restrict__ V, float* __restrict__ Og,
    float* __restrict__ Pg) {
  __shared__ __align__(16) u16 Qs[64 * 64];
  __shared__ __align__(16) u16 Ksh[64 * 64];
  __shared__ __align__(16) u16 VTs[64 * 64];
  __shared__ __align__(16) u16 Ps[64 * 64];

  const int t = threadIdx.x;
  const int lane = t & 63;
  const int w = t >> 6;
  const int cl = lane & 15;
  const int lg = lane >> 4;
  const int bx = blockIdx.x;
  const int b = bx & 7;
  const int qb = 63 - (bx >> 3);
  const int q0 = qb * 64;

  const float* Qg = Q + ((size_t)b * S_LEN + q0) * D_DIM;
  const float* Kg = K + (size_t)b * S_LEN * D_DIM;
  const float* Vg = V + (size_t)b * S_LEN * D_DIM;
  float* PgB = Pg + ((size_t)b * S_LEN + q0) * S_LEN;

  {
    int zc4 = (63 - qb) * 16;
    if (zc4 > 0) {
      f32x4 z = {0.f, 0.f, 0.f, 0.f};
      for (int r = 0; r < 64; ++r) {
        f32x4* rowp = (f32x4*)(PgB + (size_t)r * S_LEN + (size_t)(qb + 1) * 64);
        for (int c = t; c < zc4; c += 256) rowp[c] = z;
      }
    }
  }
  stageK_fn(Qs, Qg, t);
  __syncthreads();
  const int qrow = w * 16 + cl;
  bf16x8 aq0, aq1;
  {
    int b0 = qrow * 128 + ((lg * 16) ^ ((qrow & 7) << 4));
    int b1 = qrow * 128 + ((64 + lg * 16) ^ ((qrow & 7) << 4));
    aq0 = *(const bf16x8*)((char*)Qs + b0);
    aq1 = *(const bf16x8*)((char*)Qs + b1);
  }
  float psum[4] = {0.f, 0.f, 0.f, 0.f};
  for (int kt = 0; kt <= qb; ++kt) {
    __syncthreads();
    stageK_fn(Ksh, Kg + (size_t)kt * 64 * D_DIM, t);
    __syncthreads();
#pragma unroll
    for (int ct = 0; ct < 4; ++ct) {
      int krow = ct * 16 + cl;
      int bb0 = krow * 128 + ((lg * 16) ^ ((krow & 7) << 4));
      int bb1 = krow * 128 + ((64 + lg * 16) ^ ((krow & 7) << 4));
      bf16x8 bk0 = *(const bf16x8*)((char*)Ksh + bb0);
      bf16x8 bk1 = *(const bf16x8*)((char*)Ksh + bb1);
      f32x4 c = {0.f, 0.f, 0.f, 0.f};
      c = __builtin_amdgcn_mfma_f32_16x16x32_bf16(aq0, bk0, c, 0, 0, 0);
      c = __builtin_amdgcn_mfma_f32_16x16x32_bf16(aq1, bk1, c, 0, 0, 0);
      int colg = kt * 64 + ct * 16 + cl;
      int rowbase = q0 + w * 16 + lg * 4;
#pragma unroll
      for (int r = 0; r < 4; ++r) {
        float e = 0.f;
        if (colg <= rowbase + r) e = __expf(c[r] * 0.125f);
        psum[r] += e;
      }
    }
  }
  float rl[4];
#pragma unroll
  for (int r = 0; r < 4; ++r) {
    float s = psum[r];
    s += __shfl_xor(s, 1, 64);
    s += __shfl_xor(s, 2, 64);
    s += __shfl_xor(s, 4, 64);
    s += __shfl_xor(s, 8, 64);
    rl[r] = 1.0f / s;
  }
  f32x4 oacc[4];
#pragma unroll
  for (int dt = 0; dt < 4; ++dt) oacc[dt] = (f32x4){0.f, 0.f, 0.f, 0.f};
  for (int kt = 0; kt <= qb; ++kt) {
    __syncthreads();
    stageK_fn(Ksh, Kg + (size_t)kt * 64 * D_DIM, t);
    stageV_fn(VTs, Vg + (size_t)kt * 64 * D_DIM, t);
    __syncthreads();
#pragma unroll
    for (int ct = 0; ct < 4; ++ct) {
      int krow = ct * 16 + cl;
      int bb0 = krow * 128 + ((lg * 16) ^ ((krow & 7) << 4));
      int bb1 = krow * 128 + ((64 + lg * 16) ^ ((krow & 7) << 4));
      bf16x8 bk0 = *(const bf16x8*)((char*)Ksh + bb0);
      bf16x8 bk1 = *(const bf16x8*)((char*)Ksh + bb1);
      f32x4 c = {0.f, 0.f, 0.f, 0.f};
      c = __builtin_amdgcn_mfma_f32_16x16x32_bf16(aq0, bk0, c, 0, 0, 0);
      c = __builtin_amdgcn_mfma_f32_16x16x32_bf16(aq1, bk1, c, 0, 0, 0);
      int colg = kt * 64 + ct * 16 + cl;
      int rowl = w * 16 + lg * 4;
#pragma unroll
      for (int r = 0; r < 4; ++r) {
        float e = 0.f;
        if (colg <= q0 + rowl + r) e = __expf(c[r] * 0.125f);
        float p = e * rl[r];
        int pr = rowl + r;
        int byte = pr * 128 + ((((ct * 16 + cl) * 2)) ^ ((pr & 7) << 4));
        *(u16*)((char*)Ps + byte) = f2bf(p);
      }
    }
    __syncthreads();
    {
      int prow = w * 16 + cl;
      int pb0 = prow * 128 + ((lg * 16) ^ ((prow & 7) << 4));
      int pb1 = prow * 128 + ((64 + lg * 16) ^ ((prow & 7) << 4));
      bf16x8 pa0 = *(const bf16x8*)((char*)Ps + pb0);
      bf16x8 pa1 = *(const bf16x8*)((char*)Ps + pb1);
#pragma unroll
      for (int dt = 0; dt < 4; ++dt) {
        int vrow = dt * 16 + cl;
        int vb0 = vrow * 128 + ((lg * 16) ^ ((vrow & 7) << 4));
        int vb1 = vrow * 128 + ((64 + lg * 16) ^ ((vrow & 7) << 4));
        bf16x8 v0 = *(const bf16x8*)((char*)VTs + vb0);
        bf16x8 v1 = *(const bf16x8*)((char*)VTs + vb1);
        oacc[dt] = __builtin_amdgcn_mfma_f32_16x16x32_bf16(pa0, v0, oacc[dt], 0, 0, 0);
        oacc[dt] = __builtin_amdgcn_mfma_f32_16x16x32_bf16(pa1, v1, oacc[dt], 0, 0, 0);
      }
    }
#pragma unroll
    for (int j = 0; j < 2; ++j) {
      int idx = j * 256 + t;
      int pr = idx >> 3, c8 = idx & 7;
      int byte = pr * 128 + ((c8 * 16) ^ ((pr & 7) << 4));
      bf16x8 pv = *(const bf16x8*)((char*)Ps + byte);
      f32x4 f0, f1;
#pragma unroll
      for (int e = 0; e < 4; ++e) {
        f0[e] = bf2f(pv[e]);
        f1[e] = bf2f(pv[4 + e]);
      }
      f32x4* dst = (f32x4*)(PgB + (size_t)pr * S_LEN + kt * 64 + c8 * 8);
      dst[0] = f0;
      dst[1] = f1;
    }
  }
#pragma unroll
  for (int dt = 0; dt < 4; ++dt)
#pragma unroll
    for (int r = 0; r < 4; ++r)
      Og[((size_t)b * S_LEN + q0 + w * 16 + lg * 4 + r) * D_DIM + dt * 16 + cl] =
          oacc[dt][r];
}

extern "C" void kernel_launch(void* const* d_in, const int* in_sizes, int n_in,
                              void* d_out, int out_size, void* d_ws, size_t ws_size,
                              hipStream_t stream) {
  (void)in_sizes; (void)n_in; (void)out_size;
  const float* Q = (const float*)d_in[0];
  const float* K = (const float*)d_in[1];
  const float* V = (const float*)d_in[2];
  float* Og = (float*)d_out;
  float* Pg = (float*)d_out + (size_t)8 * S_LEN * D_DIM;

  const size_t need = (WSROW_FLOATS + WSO_FLOATS) * sizeof(float);
  if (d_ws != nullptr && ws_size >= need) {
    float* wsRow = (float*)d_ws;
    float* wsO = wsRow + WSROW_FLOATS;
    hipLaunchKernelGGL(k_rowsum, dim3(4096), dim3(256), 0, stream, Q, K, wsRow);
    hipLaunchKernelGGL(k_pwrite_pv, dim3(4096), dim3(256), 0, stream,
                       Q, K, V, wsRow, Pg, wsO);
    hipLaunchKernelGGL(k_ored, dim3(512), dim3(256), 0, stream, wsO, Og);
  } else {
    hipLaunchKernelGGL(attn_kernel, dim3(512), dim3(256), 0, stream, Q, K, V, Og, Pg);
  }
}